// Round 1
// 4575.576 us; speedup vs baseline: 1.0977x; 1.0977x over previous
//
#include <hip/hip_runtime.h>
#include <cstdint>
#include <cstddef>

#define CH 128
#define HH 40
#define WW 96
#define BB 64
#define HW (HH*WW)          // 3840
#define CHW ((size_t)CH*HW) // 491520

typedef _Float16 half8  __attribute__((ext_vector_type(8)));
typedef _Float16 half4v __attribute__((ext_vector_type(4)));
typedef float    float4v __attribute__((ext_vector_type(4)));

#define MFMA16(a,b,c) __builtin_amdgcn_mfma_f32_16x16x32_f16((a),(b),(c),0,0,0)

#define SPLIT_SCALE 2048.0f
#define INV_SPLIT   (1.0f/2048.0f)

#define NHWC_HALVES (BB*HH*WW*CH)   // 31,457,280 halves = 62,914,560 B
#define WSTEP_F     (CH*CH*9)       // 147,456 fp32 per step
#define WFRAG_HALVES (20*9*4*8*64*8) // 2,949,120 halves per (h|m) weight bank

// ===========================================================================
// MFMA path
// ===========================================================================

// Pre-shuffle weights into A-fragment lane order, split h/m (m scaled x2048).
// Layout: WH[((s*9+t)*4+kq)*8+mt][lane][j] ; co=mt*16+(lane&15),
// ci=kq*32+(lane>>4)*8+j.
__global__ __launch_bounds__(256) void prep_weights(
    const float* __restrict__ wd, const float* __restrict__ wu,
    const float* __restrict__ wr, const float* __restrict__ wl,
    _Float16* __restrict__ WH, _Float16* __restrict__ WM)
{
    const int bx = blockIdx.x;          // s*9 + t
    const int s = bx / 9, t = bx % 9;
    const float* src;
    if (s < 5)       src = wd + (size_t)s*WSTEP_F;
    else if (s < 10) src = wu + (size_t)(s-5)*WSTEP_F;
    else if (s < 15) src = wr + (size_t)(s-10)*WSTEP_F;
    else             src = wl + (size_t)(s-15)*WSTEP_F;

    for (int idx = threadIdx.x; idx < 2048; idx += 256) {
        const int lane = idx & 63;
        const int mt   = (idx >> 6) & 7;
        const int kq   = idx >> 9;
        const int co   = mt*16 + (lane & 15);
        const int cib  = kq*32 + (lane >> 4)*8;
        const int F    = ((((s*9 + t)*4 + kq)*8 + mt)*64 + lane)*8;
        #pragma unroll
        for (int j = 0; j < 8; ++j) {
            const float w = src[(size_t)(co*CH + (cib + j))*9 + t];
            const _Float16 h = (_Float16)w;
            WH[F + j] = h;
            WM[F + j] = (_Float16)((w - (float)h) * SPLIT_SCALE);
        }
    }
}

// fp32 NCHW -> (h,m) fp16 pair in NHWC (ci contiguous).
__global__ __launch_bounds__(256) void prep_acts(
    const float* __restrict__ x, _Float16* __restrict__ H, _Float16* __restrict__ M)
{
    __shared__ float tile[CH][33];
    const int wt = blockIdx.x, h = blockIdx.y, b = blockIdx.z;
    const int tid = threadIdx.x;
    {
        const int wl = tid & 31, c0 = tid >> 5;
        for (int it = 0; it < 16; ++it) {
            const int ci = it*8 + c0;
            tile[ci][wl] = x[((size_t)(b*CH + ci)*HH + h)*WW + wt*32 + wl];
        }
    }
    __syncthreads();
    {
        const int ci = tid & 127, w0 = tid >> 7;
        for (int it = 0; it < 16; ++it) {
            const int wl = it*2 + w0;
            const float v = tile[ci][wl];
            const _Float16 hh = (_Float16)v;
            const int o = ((b*HH + h)*WW + wt*32 + wl)*CH + ci;
            H[o] = hh;
            M[o] = (_Float16)((v - (float)hh) * SPLIT_SCALE);
        }
    }
}

// Horizontal conv (1x9 along W, pad 4), rows rolled by hoff. One block per
// (b,h): M=128 co x N=96 w, K=128 ci, 9 taps via LDS row offset.
// Scheduling: distance-1 SW pipeline on weight loads (ping-pong reg banks,
// parity = kq&1, static after unroll) + rolling 1-ahead LDS B prefetch +
// setprio around each 12-MFMA cluster. Arithmetic order unchanged.
__global__ __launch_bounds__(256, 2) void hconv_mfma(
    const _Float16* __restrict__ srcH, const _Float16* __restrict__ srcM,
    _Float16* __restrict__ dstH, _Float16* __restrict__ dstM,
    const _Float16* __restrict__ WH, const _Float16* __restrict__ WM,
    int s, int hoff)
{
    __shared__ _Float16 sB[2][104*136];   // [h|m][row 0..103][ci 0..127 pad 136]
    const int h = blockIdx.x, b = blockIdx.y;
    const int tid = threadIdx.x;
    const int hp = (h + hoff) % HH;

    {   // stage rolled row: LDS row r holds input w = r-4 (zeros in halo)
        const int l = tid & 15, r0 = tid >> 4;
        for (int it = 0; it < 7; ++it) {
            const int r = it*16 + r0;
            if (r < 104) {
                half8 vh = {}, vm = {};
                if (r >= 4 && r < 100) {
                    const int off = ((b*HH + hp)*WW + (r-4))*CH + l*8;
                    vh = *(const half8*)(srcH + off);
                    vm = *(const half8*)(srcM + off);
                }
                *(half8*)&sB[0][r*136 + l*8] = vh;
                *(half8*)&sB[1][r*136 + l*8] = vm;
            }
        }
    }
    __syncthreads();

    const int lane = tid & 63, wave = tid >> 6;
    const int n = lane & 15, quad = lane >> 4;
    const int mgrp = wave & 1, ngrp = wave >> 1;
    const int qb = quad*8;

    float4v acc0[4][3], acc1[4][3];
    #pragma unroll
    for (int i = 0; i < 4; ++i)
        #pragma unroll
        for (int j = 0; j < 3; ++j) {
            acc0[i][j] = (float4v){0.f,0.f,0.f,0.f};
            acc1[i][j] = (float4v){0.f,0.f,0.f,0.f};
        }

    int rowb[3], rb136[3];
    #pragma unroll
    for (int j = 0; j < 3; ++j) {
        rowb[j]  = (ngrp*3 + j)*16 + n;
        rb136[j] = rowb[j]*136;
    }

    // F(it) = s*147456 + it*4096 + mgrp*2048 + lane*8 ; +i*512 per mt
    const size_t Fb = (size_t)s*147456 + (size_t)(mgrp*2048 + lane*8);

    half8 Wh[2][4], Wm[2][4];
    #pragma unroll
    for (int i = 0; i < 4; ++i) {            // preload it=0 -> bank 0
        Wh[0][i] = *(const half8*)(WH + Fb + i*512);
        Wm[0][i] = *(const half8*)(WM + Fb + i*512);
    }
    half8 pbh = *(const half8*)&sB[0][rb136[0] + qb];   // (t=0,kq=0,j=0)
    half8 pbm = *(const half8*)&sB[1][rb136[0] + qb];

    for (int t = 0; t < 9; ++t) {
        #pragma unroll
        for (int kq = 0; kq < 4; ++kq) {
            const int it  = t*4 + kq;
            const int itn = (it < 35) ? it + 1 : 35;   // clamp: last prefetch harmless
            const int pc  = kq & 1;                    // static after unroll
            const int pn  = pc ^ 1;
            {   // prefetch weights for it+1 into the other bank
                const _Float16* nH = WH + Fb + (size_t)itn*4096;
                const _Float16* nM = WM + Fb + (size_t)itn*4096;
                #pragma unroll
                for (int i = 0; i < 4; ++i) {
                    Wh[pn][i] = *(const half8*)(nH + i*512);
                    Wm[pn][i] = *(const half8*)(nM + i*512);
                }
            }
            const int tn = itn >> 2, kqn = itn & 3;
            #pragma unroll
            for (int j = 0; j < 3; ++j) {
                const half8 bh = pbh, bm = pbm;
                int nro;
                if (j < 2) nro = rb136[j+1] + t*136 + kq*32 + qb;
                else       nro = rb136[0]   + tn*136 + kqn*32 + qb;
                pbh = *(const half8*)&sB[0][nro];
                pbm = *(const half8*)&sB[1][nro];
                __builtin_amdgcn_s_setprio(1);
                #pragma unroll
                for (int i = 0; i < 4; ++i) {
                    acc0[i][j] = MFMA16(Wh[pc][i], bh, acc0[i][j]);
                    acc1[i][j] = MFMA16(Wh[pc][i], bm, acc1[i][j]);
                    acc1[i][j] = MFMA16(Wm[pc][i], bh, acc1[i][j]);
                }
                __builtin_amdgcn_s_setprio(0);
            }
        }
    }

    const int spbase = (b*HH + h)*WW;
    #pragma unroll
    for (int i = 0; i < 4; ++i) {
        const int co = (mgrp*4 + i)*16 + quad*4;
        #pragma unroll
        for (int j = 0; j < 3; ++j) {
            const int w  = (ngrp*3 + j)*16 + n;
            const int sp = (spbase + w)*CH + co;
            const half4v oh = *(const half4v*)(srcH + sp);
            const half4v om = *(const half4v*)(srcM + sp);
            half4v zh, zm;
            #pragma unroll
            for (int r = 0; r < 4; ++r) {
                const float v = acc0[i][j][r] + acc1[i][j][r]*INV_SPLIT;
                const float y = (float)oh[r] + (float)om[r]*INV_SPLIT;
                const float z = y + 2.0f*fmaxf(v, 0.0f);
                const _Float16 a = (_Float16)z;
                zh[r] = a;
                zm[r] = (_Float16)((z - (float)a)*SPLIT_SCALE);
            }
            *(half4v*)(dstH + sp) = zh;
            *(half4v*)(dstM + sp) = zm;
        }
    }
}

// Vertical conv (9x1 along H, pad 4), cols rolled by woff. One block per
// (b, w-pair): 2 cols x 48 h-tile (valid 40), M=128 co. Same pipeline
// structure as hconv_mfma.
__global__ __launch_bounds__(256, 2) void vconv_mfma(
    const _Float16* __restrict__ srcH, const _Float16* __restrict__ srcM,
    _Float16* __restrict__ dstH, _Float16* __restrict__ dstM,
    const _Float16* __restrict__ WH, const _Float16* __restrict__ WM,
    int s, int woff, int final, float* __restrict__ f32out)
{
    __shared__ _Float16 sB[2][2*56*136];  // [h|m][col*56 + row][ci pad 136]
    const int wp = blockIdx.x, b = blockIdx.y;
    const int tid = threadIdx.x;

    {   // stage 2 rolled columns; LDS row p holds input h = p-4 (zeros else)
        const int l = tid & 15, r0 = tid >> 4;
        for (int it = 0; it < 7; ++it) {
            const int r = it*16 + r0;          // 0..111
            const int col = r / 56, p = r % 56;
            half8 vh = {}, vm = {};
            if (p >= 4 && p < 44) {
                const int wsrc = (wp*2 + col + woff) % WW;
                const int off = ((b*HH + (p-4))*WW + wsrc)*CH + l*8;
                vh = *(const half8*)(srcH + off);
                vm = *(const half8*)(srcM + off);
            }
            *(half8*)&sB[0][(col*56 + p)*136 + l*8] = vh;
            *(half8*)&sB[1][(col*56 + p)*136 + l*8] = vm;
        }
    }
    __syncthreads();

    const int lane = tid & 63, wave = tid >> 6;
    const int n = lane & 15, quad = lane >> 4;
    const int mgrp = wave & 1, col = wave >> 1;
    const int qb = quad*8;

    float4v acc0[4][3], acc1[4][3];
    #pragma unroll
    for (int i = 0; i < 4; ++i)
        #pragma unroll
        for (int j = 0; j < 3; ++j) {
            acc0[i][j] = (float4v){0.f,0.f,0.f,0.f};
            acc1[i][j] = (float4v){0.f,0.f,0.f,0.f};
        }

    int rowb[3], rb136[3];
    #pragma unroll
    for (int j = 0; j < 3; ++j) {
        rowb[j]  = col*56 + j*16 + n;
        rb136[j] = rowb[j]*136;
    }

    const size_t Fb = (size_t)s*147456 + (size_t)(mgrp*2048 + lane*8);

    half8 Wh[2][4], Wm[2][4];
    #pragma unroll
    for (int i = 0; i < 4; ++i) {            // preload it=0 -> bank 0
        Wh[0][i] = *(const half8*)(WH + Fb + i*512);
        Wm[0][i] = *(const half8*)(WM + Fb + i*512);
    }
    half8 pbh = *(const half8*)&sB[0][rb136[0] + qb];
    half8 pbm = *(const half8*)&sB[1][rb136[0] + qb];

    for (int t = 0; t < 9; ++t) {
        #pragma unroll
        for (int kq = 0; kq < 4; ++kq) {
            const int it  = t*4 + kq;
            const int itn = (it < 35) ? it + 1 : 35;
            const int pc  = kq & 1;
            const int pn  = pc ^ 1;
            {
                const _Float16* nH = WH + Fb + (size_t)itn*4096;
                const _Float16* nM = WM + Fb + (size_t)itn*4096;
                #pragma unroll
                for (int i = 0; i < 4; ++i) {
                    Wh[pn][i] = *(const half8*)(nH + i*512);
                    Wm[pn][i] = *(const half8*)(nM + i*512);
                }
            }
            const int tn = itn >> 2, kqn = itn & 3;
            #pragma unroll
            for (int j = 0; j < 3; ++j) {
                const half8 bh = pbh, bm = pbm;
                int nro;
                if (j < 2) nro = rb136[j+1] + t*136 + kq*32 + qb;
                else       nro = rb136[0]   + tn*136 + kqn*32 + qb;
                pbh = *(const half8*)&sB[0][nro];
                pbm = *(const half8*)&sB[1][nro];
                __builtin_amdgcn_s_setprio(1);
                #pragma unroll
                for (int i = 0; i < 4; ++i) {
                    acc0[i][j] = MFMA16(Wh[pc][i], bh, acc0[i][j]);
                    acc1[i][j] = MFMA16(Wh[pc][i], bm, acc1[i][j]);
                    acc1[i][j] = MFMA16(Wm[pc][i], bh, acc1[i][j]);
                }
                __builtin_amdgcn_s_setprio(0);
            }
        }
    }

    const int w_out = wp*2 + col;
    #pragma unroll
    for (int i = 0; i < 4; ++i) {
        const int co = (mgrp*4 + i)*16 + quad*4;
        #pragma unroll
        for (int j = 0; j < 3; ++j) {
            const int h_out = j*16 + n;
            if (h_out < HH) {
                const int sp = ((b*HH + h_out)*WW + w_out)*CH + co;
                const half4v oh = *(const half4v*)(srcH + sp);
                const half4v om = *(const half4v*)(srcM + sp);
                if (final) {
                    float4v z4;
                    #pragma unroll
                    for (int r = 0; r < 4; ++r) {
                        const float v = acc0[i][j][r] + acc1[i][j][r]*INV_SPLIT;
                        const float y = (float)oh[r] + (float)om[r]*INV_SPLIT;
                        z4[r] = y + 2.0f*fmaxf(v, 0.0f);
                    }
                    *(float4v*)(f32out + sp) = z4;
                } else {
                    half4v zh, zm;
                    #pragma unroll
                    for (int r = 0; r < 4; ++r) {
                        const float v = acc0[i][j][r] + acc1[i][j][r]*INV_SPLIT;
                        const float y = (float)oh[r] + (float)om[r]*INV_SPLIT;
                        const float z = y + 2.0f*fmaxf(v, 0.0f);
                        const _Float16 a = (_Float16)z;
                        zh[r] = a;
                        zm[r] = (_Float16)((z - (float)a)*SPLIT_SCALE);
                    }
                    *(half4v*)(dstH + sp) = zh;
                    *(half4v*)(dstM + sp) = zm;
                }
            }
        }
    }
}

// fp32 NHWC -> fp32 NCHW (final output)
__global__ __launch_bounds__(256) void nhwc_to_nchw(
    const float* __restrict__ src, float* __restrict__ dst)
{
    __shared__ float tile[32][133];
    const int wt = blockIdx.x, h = blockIdx.y, b = blockIdx.z;
    const int tid = threadIdx.x;
    {
        const int ci = tid & 127, w0 = tid >> 7;
        for (int it = 0; it < 16; ++it) {
            const int wl = it*2 + w0;
            tile[wl][ci] = src[((size_t)(b*HH + h)*WW + wt*32 + wl)*CH + ci];
        }
    }
    __syncthreads();
    {
        const int wl = tid & 31, c0 = tid >> 5;
        for (int it = 0; it < 16; ++it) {
            const int ci = it*8 + c0;
            dst[((size_t)(b*CH + ci)*HH + h)*WW + wt*32 + wl] = tile[wl][ci];
        }
    }
}

// ===========================================================================
// Fallback fp32 vector path (round-1, proven correct) — used if ws too small.
// ===========================================================================
__global__ __launch_bounds__(256) void hconv_step(
    const float* __restrict__ src, const float* __restrict__ wgt,
    float* __restrict__ dst, int hoff)
{
    __shared__ float ld[CH][104];
    const int h = blockIdx.x, b = blockIdx.y, tid = threadIdx.x;
    const int hp = (h + hoff) % HH;
    const float* srow = src + (size_t)b*CHW + (size_t)hp*WW;
    for (int idx = tid; idx < CH*24; idx += 256) {
        int ci = idx / 24, j = idx % 24;
        float4 v = *reinterpret_cast<const float4*>(srow + (size_t)ci*HW + j*4);
        *reinterpret_cast<float4*>(&ld[ci][4 + 4*j]) = v;
    }
    if (tid < CH) {
        *reinterpret_cast<float4*>(&ld[tid][0])   = make_float4(0.f,0.f,0.f,0.f);
        *reinterpret_cast<float4*>(&ld[tid][100]) = make_float4(0.f,0.f,0.f,0.f);
    }
    __syncthreads();
    const int tx = tid & 7, ty = tid >> 3;
    const int w0 = tx*12, co0 = ty*4;
    float acc[4][12];
    #pragma unroll
    for (int c = 0; c < 4; ++c)
        #pragma unroll
        for (int k = 0; k < 12; ++k) acc[c][k] = 0.f;
    const float* wb = wgt + (size_t)co0*(CH*9);
    for (int ci = 0; ci < CH; ++ci) {
        float xr[20];
        #pragma unroll
        for (int j = 0; j < 5; ++j) {
            float4 v = *reinterpret_cast<const float4*>(&ld[ci][w0 + 4*j]);
            xr[4*j+0]=v.x; xr[4*j+1]=v.y; xr[4*j+2]=v.z; xr[4*j+3]=v.w;
        }
        #pragma unroll
        for (int c = 0; c < 4; ++c) {
            const float* wp = wb + (size_t)c*(CH*9) + ci*9;
            #pragma unroll
            for (int t = 0; t < 9; ++t) {
                const float wv = wp[t];
                #pragma unroll
                for (int k = 0; k < 12; ++k) acc[c][k] = fmaf(wv, xr[k+t], acc[c][k]);
            }
        }
    }
    const size_t obase = (size_t)b*CHW + (size_t)h*WW + w0;
    #pragma unroll
    for (int c = 0; c < 4; ++c) {
        const size_t o = obase + (size_t)(co0 + c)*HW;
        #pragma unroll
        for (int j = 0; j < 3; ++j) {
            float4 s = *reinterpret_cast<const float4*>(src + o + 4*j);
            float4 r;
            r.x = s.x + 2.f*fmaxf(acc[c][4*j+0], 0.f);
            r.y = s.y + 2.f*fmaxf(acc[c][4*j+1], 0.f);
            r.z = s.z + 2.f*fmaxf(acc[c][4*j+2], 0.f);
            r.w = s.w + 2.f*fmaxf(acc[c][4*j+3], 0.f);
            *reinterpret_cast<float4*>(dst + o + 4*j) = r;
        }
    }
}

__global__ __launch_bounds__(256) void vconv_step(
    const float* __restrict__ src, const float* __restrict__ wgt,
    float* __restrict__ dst, int woff)
{
    __shared__ float ld[CH][2][48];
    const int w0 = blockIdx.x*2, b = blockIdx.y, tid = threadIdx.x;
    const int w1 = (w0 + woff) % WW, w2 = (w0 + 1 + woff) % WW;
    const float* sb = src + (size_t)b*CHW;
    for (int idx = tid; idx < CH*HH; idx += 256) {
        int ci = idx / HH, hh = idx % HH;
        const float* p = sb + (size_t)ci*HW + (size_t)hh*WW;
        ld[ci][0][4 + hh] = p[w1];
        ld[ci][1][4 + hh] = p[w2];
    }
    if (tid < CH) {
        #pragma unroll
        for (int j = 0; j < 4; ++j) {
            ld[tid][0][j]=0.f; ld[tid][0][44+j]=0.f;
            ld[tid][1][j]=0.f; ld[tid][1][44+j]=0.f;
        }
    }
    __syncthreads();
    const int tx = tid & 7, ty = tid >> 3;
    const int wi = tx >> 2, h0 = (tx & 3)*10, co0 = ty*4;
    float acc[4][10];
    #pragma unroll
    for (int c = 0; c < 4; ++c)
        #pragma unroll
        for (int k = 0; k < 10; ++k) acc[c][k] = 0.f;
    const float* wb = wgt + (size_t)co0*(CH*9);
    for (int ci = 0; ci < CH; ++ci) {
        float xr[18];
        #pragma unroll
        for (int j = 0; j < 18; ++j) xr[j] = ld[ci][wi][h0 + j];
        #pragma unroll
        for (int c = 0; c < 4; ++c) {
            const float* wp = wb + (size_t)c*(CH*9) + ci*9;
            #pragma unroll
            for (int t = 0; t < 9; ++t) {
                const float wv = wp[t];
                #pragma unroll
                for (int k = 0; k < 10; ++k) acc[c][k] = fmaf(wv, xr[k+t], acc[c][k]);
            }
        }
    }
    #pragma unroll
    for (int c = 0; c < 4; ++c) {
        const size_t o = (size_t)b*CHW + (size_t)(co0 + c)*HW + (size_t)h0*WW + (w0 + wi);
        #pragma unroll
        for (int k = 0; k < 10; ++k) {
            const float s = src[o + (size_t)k*WW];
            dst[o + (size_t)k*WW] = s + 2.f*fmaxf(acc[c][k], 0.f);
        }
    }
}

// ===========================================================================
extern "C" void kernel_launch(void* const* d_in, const int* in_sizes, int n_in,
                              void* d_out, int out_size, void* d_ws, size_t ws_size,
                              hipStream_t stream)
{
    const float* x  = (const float*)d_in[0];
    const float* wd = (const float*)d_in[1];
    const float* wu = (const float*)d_in[2];
    const float* wr = (const float*)d_in[3];
    const float* wl = (const float*)d_in[4];

    const size_t NEED = 125829120ULL + 2ULL*WFRAG_HALVES*2ULL;  // 137,625,600 B

    if (ws_size >= NEED) {
        _Float16* HA  = (_Float16*)d_ws;
        _Float16* MA  = HA + NHWC_HALVES;
        _Float16* WHp = (_Float16*)((char*)d_ws + 125829120ULL);
        _Float16* WMp = WHp + WFRAG_HALVES;
        _Float16* HB  = (_Float16*)d_out;
        _Float16* MB  = HB + NHWC_HALVES;
        float* f32tmp = (float*)d_ws;   // reuses the A-pair region (dead by then)

        prep_weights<<<dim3(180), 256, 0, stream>>>(wd, wu, wr, wl, WHp, WMp);
        prep_acts<<<dim3(3, HH, BB), 256, 0, stream>>>(x, HA, MA);

        const int hoffs[10] = {1,2,5,10,20, 39,38,35,30,20};     // wd: +off, wu: H-off
        for (int s = 0; s < 10; ++s) {
            const _Float16* sH = (s & 1) ? HB : HA;
            const _Float16* sM = (s & 1) ? MB : MA;
            _Float16* dH = (s & 1) ? HA : HB;
            _Float16* dM = (s & 1) ? MA : MB;
            hconv_mfma<<<dim3(HH, BB), 256, 0, stream>>>(sH, sM, dH, dM,
                                                         WHp, WMp, s, hoffs[s]);
        }
        const int woffs[10] = {3,6,12,24,48, 93,90,84,72,48};    // wr: +off, wl: W-off
        for (int k = 0; k < 10; ++k) {
            const int s = 10 + k;
            const _Float16* sH = (s & 1) ? HB : HA;
            const _Float16* sM = (s & 1) ? MB : MA;
            _Float16* dH = (s & 1) ? HA : HB;
            _Float16* dM = (s & 1) ? MA : MB;
            const int fin = (s == 19);
            vconv_mfma<<<dim3(WW/2, BB), 256, 0, stream>>>(sH, sM, dH, dM,
                                                           WHp, WMp, s, woffs[k],
                                                           fin, f32tmp);
        }
        nhwc_to_nchw<<<dim3(3, HH, BB), 256, 0, stream>>>(f32tmp, (float*)d_out);
    } else {
        // fp32 fallback (round-1 path)
        float* out = (float*)d_out;
        float* ws  = (float*)d_ws;
        const size_t WSTEP = (size_t)WSTEP_F;
        const int hoffs[5] = {1, 2, 5, 10, 20};
        const int woffs[5] = {3, 6, 12, 24, 48};
        dim3 hgrid(HH, BB), vgrid(WW/2, BB);
        const float* src = x;
        int step = 0;
        for (int i = 0; i < 5; ++i) {
            float* dst = (step & 1) ? out : ws;
            hconv_step<<<hgrid, 256, 0, stream>>>(src, wd + i*WSTEP, dst, hoffs[i]);
            src = dst; ++step;
        }
        for (int i = 0; i < 5; ++i) {
            float* dst = (step & 1) ? out : ws;
            hconv_step<<<hgrid, 256, 0, stream>>>(src, wu + i*WSTEP, dst, (HH - hoffs[i]) % HH);
            src = dst; ++step;
        }
        for (int i = 0; i < 5; ++i) {
            float* dst = (step & 1) ? out : ws;
            vconv_step<<<vgrid, 256, 0, stream>>>(src, wr + i*WSTEP, dst, woffs[i]);
            src = dst; ++step;
        }
        for (int i = 0; i < 5; ++i) {
            float* dst = (step & 1) ? out : ws;
            vconv_step<<<vgrid, 256, 0, stream>>>(src, wl + i*WSTEP, dst, (WW - woffs[i]) % WW);
            src = dst; ++step;
        }
    }
}

// Round 2
// 4485.049 us; speedup vs baseline: 1.1199x; 1.0202x over previous
//
#include <hip/hip_runtime.h>
#include <cstdint>
#include <cstddef>

#define CH 128
#define HH 40
#define WW 96
#define BB 64
#define HW (HH*WW)          // 3840
#define CHW ((size_t)CH*HW) // 491520

typedef _Float16 half8  __attribute__((ext_vector_type(8)));
typedef _Float16 half4v __attribute__((ext_vector_type(4)));
typedef float    float4v __attribute__((ext_vector_type(4)));

#define MFMA16(a,b,c) __builtin_amdgcn_mfma_f32_16x16x32_f16((a),(b),(c),0,0,0)

#define SPLIT_SCALE 2048.0f
#define INV_SPLIT   (1.0f/2048.0f)

#define NHWC_HALVES (BB*HH*WW*CH)   // 31,457,280 halves = 62,914,560 B
#define WSTEP_F     (CH*CH*9)       // 147,456 fp32 per step
#define WFRAG_HALVES (20*9*4*8*64*8) // 2,949,120 halves per (h|m) weight bank

// Direct global->LDS (wave-uniform LDS base + lane*16; per-lane global src).
__device__ __forceinline__ void gload16(const _Float16* g, _Float16* l) {
    __builtin_amdgcn_global_load_lds(
        (const __attribute__((address_space(1))) void*)g,
        (__attribute__((address_space(3))) void*)l,
        16, 0, 0);
}

// ===========================================================================
// MFMA path
// ===========================================================================

// Pre-shuffle weights into A-fragment lane order, split h/m (m scaled x2048).
// Layout: WH[((s*9+t)*4+kq)*8+mt][lane][j] ; co=mt*16+(lane&15),
// ci=kq*32+(lane>>4)*8+j.
__global__ __launch_bounds__(256) void prep_weights(
    const float* __restrict__ wd, const float* __restrict__ wu,
    const float* __restrict__ wr, const float* __restrict__ wl,
    _Float16* __restrict__ WH, _Float16* __restrict__ WM)
{
    const int bx = blockIdx.x;          // s*9 + t
    const int s = bx / 9, t = bx % 9;
    const float* src;
    if (s < 5)       src = wd + (size_t)s*WSTEP_F;
    else if (s < 10) src = wu + (size_t)(s-5)*WSTEP_F;
    else if (s < 15) src = wr + (size_t)(s-10)*WSTEP_F;
    else             src = wl + (size_t)(s-15)*WSTEP_F;

    for (int idx = threadIdx.x; idx < 2048; idx += 256) {
        const int lane = idx & 63;
        const int mt   = (idx >> 6) & 7;
        const int kq   = idx >> 9;
        const int co   = mt*16 + (lane & 15);
        const int cib  = kq*32 + (lane >> 4)*8;
        const int F    = ((((s*9 + t)*4 + kq)*8 + mt)*64 + lane)*8;
        #pragma unroll
        for (int j = 0; j < 8; ++j) {
            const float w = src[(size_t)(co*CH + (cib + j))*9 + t];
            const _Float16 h = (_Float16)w;
            WH[F + j] = h;
            WM[F + j] = (_Float16)((w - (float)h) * SPLIT_SCALE);
        }
    }
}

// fp32 NCHW -> (h,m) fp16 pair in NHWC (ci contiguous).
__global__ __launch_bounds__(256) void prep_acts(
    const float* __restrict__ x, _Float16* __restrict__ H, _Float16* __restrict__ M)
{
    __shared__ float tile[CH][33];
    const int wt = blockIdx.x, h = blockIdx.y, b = blockIdx.z;
    const int tid = threadIdx.x;
    {
        const int wl = tid & 31, c0 = tid >> 5;
        for (int it = 0; it < 16; ++it) {
            const int ci = it*8 + c0;
            tile[ci][wl] = x[((size_t)(b*CH + ci)*HH + h)*WW + wt*32 + wl];
        }
    }
    __syncthreads();
    {
        const int ci = tid & 127, w0 = tid >> 7;
        for (int it = 0; it < 16; ++it) {
            const int wl = it*2 + w0;
            const float v = tile[ci][wl];
            const _Float16 hh = (_Float16)v;
            const int o = ((b*HH + h)*WW + wt*32 + wl)*CH + ci;
            H[o] = hh;
            M[o] = (_Float16)((v - (float)hh) * SPLIT_SCALE);
        }
    }
}

// Horizontal conv (1x9 along W, pad 4), rows rolled by hoff. One block per
// (b,h): M=128 co x N=96 w, K=128 ci, 9 taps via LDS row offset.
// LDS: pitch 128 halves (256B rows) + XOR swizzle ((row&7)<<3 on half index)
// -> 2-way max bank aliasing on ds_read_b128. Staging via global_load_lds
// (linear LDS dest, inverse-swizzled per-lane GLOBAL source — involution).
__global__ __launch_bounds__(256, 2) void hconv_mfma(
    const _Float16* __restrict__ srcH, const _Float16* __restrict__ srcM,
    _Float16* __restrict__ dstH, _Float16* __restrict__ dstM,
    const _Float16* __restrict__ WH, const _Float16* __restrict__ WM,
    int s, int hoff)
{
    __shared__ _Float16 sB[2][104*128];   // [h|m][row 0..103][ci 0..127]
    const int h = blockIdx.x, b = blockIdx.y;
    const int tid = threadIdx.x;
    const int hp = (h + hoff) % HH;
    const int lane = tid & 63, wave = tid >> 6;

    {   // stage rows 4..99 (input w = row-4) : 24 chunks of 4 rows, 6/wave
        const int rr = lane >> 4, slot = lane & 15;
        #pragma unroll
        for (int k = 0; k < 6; ++k) {
            const int c = wave*6 + k;
            const int rbase = 4 + 4*c;            // LDS row base (mult of 4)
            const int row = rbase + rr;
            const size_t goff = ((size_t)(b*HH + hp)*WW + (rbase - 4))*CH;
            const int so = rr*CH + ((slot ^ (row & 7))*8);
            gload16(srcH + goff + so, (_Float16*)&sB[0][rbase*128]);
            gload16(srcM + goff + so, (_Float16*)&sB[1][rbase*128]);
        }
        // zero halos: rows 0..3 and 100..103, both arrays (4 rows = 512 halves)
        const int zrow = (wave & 1)*100;
        const int arr  = wave >> 1;
        *(half8*)&sB[arr][zrow*128 + lane*8] = (half8){};
    }
    __syncthreads();

    const int n = lane & 15, quad = lane >> 4;
    const int mgrp = wave & 1, ngrp = wave >> 1;
    const int qs = quad*8;
#define BADDR(row, kq) ((row)*128 + ((((kq)*32) + qs) ^ ((((row) & 7)) << 3)))

    float4v acc0[4][3], acc1[4][3];
    #pragma unroll
    for (int i = 0; i < 4; ++i)
        #pragma unroll
        for (int j = 0; j < 3; ++j) {
            acc0[i][j] = (float4v){0.f,0.f,0.f,0.f};
            acc1[i][j] = (float4v){0.f,0.f,0.f,0.f};
        }

    int rowb[3];
    #pragma unroll
    for (int j = 0; j < 3; ++j) rowb[j] = (ngrp*3 + j)*16 + n;

    // F(it) = s*147456 + it*4096 + mgrp*2048 + lane*8 ; +i*512 per mt
    const size_t Fb = (size_t)s*147456 + (size_t)(mgrp*2048 + lane*8);

    half8 Wh[2][4], Wm[2][4];
    #pragma unroll
    for (int i = 0; i < 4; ++i) {            // preload it=0 -> bank 0
        Wh[0][i] = *(const half8*)(WH + Fb + i*512);
        Wm[0][i] = *(const half8*)(WM + Fb + i*512);
    }
    half8 pbh = *(const half8*)&sB[0][BADDR(rowb[0], 0)];   // (t=0,kq=0,j=0)
    half8 pbm = *(const half8*)&sB[1][BADDR(rowb[0], 0)];

    for (int t = 0; t < 9; ++t) {
        #pragma unroll
        for (int kq = 0; kq < 4; ++kq) {
            const int it  = t*4 + kq;
            const int itn = (it < 35) ? it + 1 : 35;   // clamp: last prefetch harmless
            const int pc  = kq & 1;                    // static after unroll
            const int pn  = pc ^ 1;
            {   // prefetch weights for it+1 into the other bank
                const _Float16* nH = WH + Fb + (size_t)itn*4096;
                const _Float16* nM = WM + Fb + (size_t)itn*4096;
                #pragma unroll
                for (int i = 0; i < 4; ++i) {
                    Wh[pn][i] = *(const half8*)(nH + i*512);
                    Wm[pn][i] = *(const half8*)(nM + i*512);
                }
            }
            const int tn = itn >> 2, kqn = itn & 3;
            #pragma unroll
            for (int j = 0; j < 3; ++j) {
                const half8 bh = pbh, bm = pbm;
                int nro;
                if (j < 2) nro = BADDR(rowb[j+1] + t, kq);
                else       nro = BADDR(rowb[0] + tn, kqn);
                pbh = *(const half8*)&sB[0][nro];
                pbm = *(const half8*)&sB[1][nro];
                __builtin_amdgcn_s_setprio(1);
                #pragma unroll
                for (int i = 0; i < 4; ++i) {
                    acc0[i][j] = MFMA16(Wh[pc][i], bh, acc0[i][j]);
                    acc1[i][j] = MFMA16(Wh[pc][i], bm, acc1[i][j]);
                    acc1[i][j] = MFMA16(Wm[pc][i], bh, acc1[i][j]);
                }
                __builtin_amdgcn_s_setprio(0);
            }
        }
    }
#undef BADDR

    const int spbase = (b*HH + h)*WW;
    #pragma unroll
    for (int i = 0; i < 4; ++i) {
        const int co = (mgrp*4 + i)*16 + quad*4;
        #pragma unroll
        for (int j = 0; j < 3; ++j) {
            const int w  = (ngrp*3 + j)*16 + n;
            const int sp = (spbase + w)*CH + co;
            const half4v oh = *(const half4v*)(srcH + sp);
            const half4v om = *(const half4v*)(srcM + sp);
            half4v zh, zm;
            #pragma unroll
            for (int r = 0; r < 4; ++r) {
                const float v = acc0[i][j][r] + acc1[i][j][r]*INV_SPLIT;
                const float y = (float)oh[r] + (float)om[r]*INV_SPLIT;
                const float z = y + 2.0f*fmaxf(v, 0.0f);
                const _Float16 a = (_Float16)z;
                zh[r] = a;
                zm[r] = (_Float16)((z - (float)a)*SPLIT_SCALE);
            }
            *(half4v*)(dstH + sp) = zh;
            *(half4v*)(dstM + sp) = zm;
        }
    }
}

// Vertical conv (9x1 along H, pad 4), cols rolled by woff. One block per
// (b, w-pair). N remapped to 2 cols x 40 valid h = 80 outputs = exactly 5
// tiles of 16 (zero wasted MFMAs): o=j*16+n, col=(o>=40), LDS row=o+8*col+t.
// Wave split: mgrp(2) x j-set {0,1,2 | 3,4} (wave-uniform static guard).
__global__ __launch_bounds__(256, 2) void vconv_mfma(
    const _Float16* __restrict__ srcH, const _Float16* __restrict__ srcM,
    _Float16* __restrict__ dstH, _Float16* __restrict__ dstM,
    const _Float16* __restrict__ WH, const _Float16* __restrict__ WM,
    int s, int woff, int final, float* __restrict__ f32out)
{
    __shared__ _Float16 sB[2][96*128];  // [h|m][col*48 + (h_in+4)][ci]
    const int wp = blockIdx.x, b = blockIdx.y;
    const int tid = threadIdx.x;
    const int lane = tid & 63, wave = tid >> 6;

    {   // stage 2 cols x 40 valid rows: 20 chunks of 4 rows, 5/wave
        const int rr = lane >> 4, slot = lane & 15;
        for (int k = wave; k < 20; k += 4) {
            const int col = (k >= 10);
            const int c = k - col*10;
            const int rbase = col*48 + 4 + 4*c;   // LDS row base (mult of 4)
            const int h0 = 4*c;                   // global h base
            const int wsrc = (wp*2 + col + woff) % WW;
            const size_t goff = ((size_t)(b*HH + h0)*WW + wsrc)*CH;
            const int row = rbase + rr;
            const int so = rr*(WW*CH) + ((slot ^ (row & 7))*8);
            gload16(srcH + goff + so, (_Float16*)&sB[0][rbase*128]);
            gload16(srcM + goff + so, (_Float16*)&sB[1][rbase*128]);
        }
        // zero halos: row bases {0,44,48,92}, 4 rows each, both arrays
        const int zrow = (wave & 1)*44 + (wave >> 1)*48;
        *(half8*)&sB[0][zrow*128 + lane*8] = (half8){};
        *(half8*)&sB[1][zrow*128 + lane*8] = (half8){};
    }
    __syncthreads();

    const int n = lane & 15, quad = lane >> 4;
    const int mgrp = wave & 1;
    const int jbase = (wave >> 1)*3;          // 0 or 3
    const bool has3 = (wave >> 1) == 0;       // waves 0,1: j{0,1,2}; 2,3: j{3,4}
    const int qs = quad*8;
#define BADDR(row, kq) ((row)*128 + ((((kq)*32) + qs) ^ ((((row) & 7)) << 3)))

    float4v acc0[4][3], acc1[4][3];
    #pragma unroll
    for (int i = 0; i < 4; ++i)
        #pragma unroll
        for (int j = 0; j < 3; ++j) {
            acc0[i][j] = (float4v){0.f,0.f,0.f,0.f};
            acc1[i][j] = (float4v){0.f,0.f,0.f,0.f};
        }

    int rowbse[3];
    #pragma unroll
    for (int jj = 0; jj < 3; ++jj) {
        int o = (jbase + jj)*16 + n;
        if (o > 79) o = 79;                   // clamp (unused slots only)
        const int col = (o >= 40);
        rowbse[jj] = o + 8*col;               // halo'd LDS row base (t adds 0..8)
    }

    const size_t Fb = (size_t)s*147456 + (size_t)(mgrp*2048 + lane*8);

    half8 Wh[2][4], Wm[2][4];
    #pragma unroll
    for (int i = 0; i < 4; ++i) {            // preload it=0 -> bank 0
        Wh[0][i] = *(const half8*)(WH + Fb + i*512);
        Wm[0][i] = *(const half8*)(WM + Fb + i*512);
    }
    half8 pbh = *(const half8*)&sB[0][BADDR(rowbse[0], 0)];
    half8 pbm = *(const half8*)&sB[1][BADDR(rowbse[0], 0)];

    for (int t = 0; t < 9; ++t) {
        #pragma unroll
        for (int kq = 0; kq < 4; ++kq) {
            const int it  = t*4 + kq;
            const int itn = (it < 35) ? it + 1 : 35;
            const int pc  = kq & 1;
            const int pn  = pc ^ 1;
            {
                const _Float16* nH = WH + Fb + (size_t)itn*4096;
                const _Float16* nM = WM + Fb + (size_t)itn*4096;
                #pragma unroll
                for (int i = 0; i < 4; ++i) {
                    Wh[pn][i] = *(const half8*)(nH + i*512);
                    Wm[pn][i] = *(const half8*)(nM + i*512);
                }
            }
            const int tn = itn >> 2, kqn = itn & 3;
            #pragma unroll
            for (int jj = 0; jj < 3; ++jj) {
                if (jj != 2 || has3) {        // wave-uniform; folds for jj<2
                    const half8 bh = pbh, bm = pbm;
                    int nro;
                    if (jj == 0)      nro = BADDR(rowbse[1] + t, kq);
                    else if (jj == 1) nro = has3 ? BADDR(rowbse[2] + t, kq)
                                                 : BADDR(rowbse[0] + tn, kqn);
                    else              nro = BADDR(rowbse[0] + tn, kqn);
                    pbh = *(const half8*)&sB[0][nro];
                    pbm = *(const half8*)&sB[1][nro];
                    __builtin_amdgcn_s_setprio(1);
                    #pragma unroll
                    for (int i = 0; i < 4; ++i) {
                        acc0[i][jj] = MFMA16(Wh[pc][i], bh, acc0[i][jj]);
                        acc1[i][jj] = MFMA16(Wh[pc][i], bm, acc1[i][jj]);
                        acc1[i][jj] = MFMA16(Wm[pc][i], bh, acc1[i][jj]);
                    }
                    __builtin_amdgcn_s_setprio(0);
                }
            }
        }
    }
#undef BADDR

    #pragma unroll
    for (int i = 0; i < 4; ++i) {
        const int co = (mgrp*4 + i)*16 + quad*4;
        #pragma unroll
        for (int jj = 0; jj < 3; ++jj) {
            if (jj != 2 || has3) {
                const int o = (jbase + jj)*16 + n;     // 0..79, all valid
                const int col = (o >= 40);
                const int h_out = o - 40*col;
                const int w_out = wp*2 + col;
                const int sp = ((b*HH + h_out)*WW + w_out)*CH + co;
                const half4v oh = *(const half4v*)(srcH + sp);
                const half4v om = *(const half4v*)(srcM + sp);
                if (final) {
                    float4v z4;
                    #pragma unroll
                    for (int r = 0; r < 4; ++r) {
                        const float v = acc0[i][jj][r] + acc1[i][jj][r]*INV_SPLIT;
                        const float y = (float)oh[r] + (float)om[r]*INV_SPLIT;
                        z4[r] = y + 2.0f*fmaxf(v, 0.0f);
                    }
                    *(float4v*)(f32out + sp) = z4;
                } else {
                    half4v zh, zm;
                    #pragma unroll
                    for (int r = 0; r < 4; ++r) {
                        const float v = acc0[i][jj][r] + acc1[i][jj][r]*INV_SPLIT;
                        const float y = (float)oh[r] + (float)om[r]*INV_SPLIT;
                        const float z = y + 2.0f*fmaxf(v, 0.0f);
                        const _Float16 a = (_Float16)z;
                        zh[r] = a;
                        zm[r] = (_Float16)((z - (float)a)*SPLIT_SCALE);
                    }
                    *(half4v*)(dstH + sp) = zh;
                    *(half4v*)(dstM + sp) = zm;
                }
            }
        }
    }
}

// fp32 NHWC -> fp32 NCHW (final output)
__global__ __launch_bounds__(256) void nhwc_to_nchw(
    const float* __restrict__ src, float* __restrict__ dst)
{
    __shared__ float tile[32][133];
    const int wt = blockIdx.x, h = blockIdx.y, b = blockIdx.z;
    const int tid = threadIdx.x;
    {
        const int ci = tid & 127, w0 = tid >> 7;
        for (int it = 0; it < 16; ++it) {
            const int wl = it*2 + w0;
            tile[wl][ci] = src[((size_t)(b*HH + h)*WW + wt*32 + wl)*CH + ci];
        }
    }
    __syncthreads();
    {
        const int wl = tid & 31, c0 = tid >> 5;
        for (int it = 0; it < 16; ++it) {
            const int ci = it*8 + c0;
            dst[((size_t)(b*CH + ci)*HH + h)*WW + wt*32 + wl] = tile[wl][ci];
        }
    }
}

// ===========================================================================
// Fallback fp32 vector path (round-1, proven correct) — used if ws too small.
// ===========================================================================
__global__ __launch_bounds__(256) void hconv_step(
    const float* __restrict__ src, const float* __restrict__ wgt,
    float* __restrict__ dst, int hoff)
{
    __shared__ float ld[CH][104];
    const int h = blockIdx.x, b = blockIdx.y, tid = threadIdx.x;
    const int hp = (h + hoff) % HH;
    const float* srow = src + (size_t)b*CHW + (size_t)hp*WW;
    for (int idx = tid; idx < CH*24; idx += 256) {
        int ci = idx / 24, j = idx % 24;
        float4 v = *reinterpret_cast<const float4*>(srow + (size_t)ci*HW + j*4);
        *reinterpret_cast<float4*>(&ld[ci][4 + 4*j]) = v;
    }
    if (tid < CH) {
        *reinterpret_cast<float4*>(&ld[tid][0])   = make_float4(0.f,0.f,0.f,0.f);
        *reinterpret_cast<float4*>(&ld[tid][100]) = make_float4(0.f,0.f,0.f,0.f);
    }
    __syncthreads();
    const int tx = tid & 7, ty = tid >> 3;
    const int w0 = tx*12, co0 = ty*4;
    float acc[4][12];
    #pragma unroll
    for (int c = 0; c < 4; ++c)
        #pragma unroll
        for (int k = 0; k < 12; ++k) acc[c][k] = 0.f;
    const float* wb = wgt + (size_t)co0*(CH*9);
    for (int ci = 0; ci < CH; ++ci) {
        float xr[20];
        #pragma unroll
        for (int j = 0; j < 5; ++j) {
            float4 v = *reinterpret_cast<const float4*>(&ld[ci][w0 + 4*j]);
            xr[4*j+0]=v.x; xr[4*j+1]=v.y; xr[4*j+2]=v.z; xr[4*j+3]=v.w;
        }
        #pragma unroll
        for (int c = 0; c < 4; ++c) {
            const float* wp = wb + (size_t)c*(CH*9) + ci*9;
            #pragma unroll
            for (int t = 0; t < 9; ++t) {
                const float wv = wp[t];
                #pragma unroll
                for (int k = 0; k < 12; ++k) acc[c][k] = fmaf(wv, xr[k+t], acc[c][k]);
            }
        }
    }
    const size_t obase = (size_t)b*CHW + (size_t)h*WW + w0;
    #pragma unroll
    for (int c = 0; c < 4; ++c) {
        const size_t o = obase + (size_t)(co0 + c)*HW;
        #pragma unroll
        for (int j = 0; j < 3; ++j) {
            float4 s = *reinterpret_cast<const float4*>(src + o + 4*j);
            float4 r;
            r.x = s.x + 2.f*fmaxf(acc[c][4*j+0], 0.f);
            r.y = s.y + 2.f*fmaxf(acc[c][4*j+1], 0.f);
            r.z = s.z + 2.f*fmaxf(acc[c][4*j+2], 0.f);
            r.w = s.w + 2.f*fmaxf(acc[c][4*j+3], 0.f);
            *reinterpret_cast<float4*>(dst + o + 4*j) = r;
        }
    }
}

__global__ __launch_bounds__(256) void vconv_step(
    const float* __restrict__ src, const float* __restrict__ wgt,
    float* __restrict__ dst, int woff)
{
    __shared__ float ld[CH][2][48];
    const int w0 = blockIdx.x*2, b = blockIdx.y, tid = threadIdx.x;
    const int w1 = (w0 + woff) % WW, w2 = (w0 + 1 + woff) % WW;
    const float* sb = src + (size_t)b*CHW;
    for (int idx = tid; idx < CH*HH; idx += 256) {
        int ci = idx / HH, hh = idx % HH;
        const float* p = sb + (size_t)ci*HW + (size_t)hh*WW;
        ld[ci][0][4 + hh] = p[w1];
        ld[ci][1][4 + hh] = p[w2];
    }
    if (tid < CH) {
        #pragma unroll
        for (int j = 0; j < 4; ++j) {
            ld[tid][0][j]=0.f; ld[tid][0][44+j]=0.f;
            ld[tid][1][j]=0.f; ld[tid][1][44+j]=0.f;
        }
    }
    __syncthreads();
    const int tx = tid & 7, ty = tid >> 3;
    const int wi = tx >> 2, h0 = (tx & 3)*10, co0 = ty*4;
    float acc[4][10];
    #pragma unroll
    for (int c = 0; c < 4; ++c)
        #pragma unroll
        for (int k = 0; k < 10; ++k) acc[c][k] = 0.f;
    const float* wb = wgt + (size_t)co0*(CH*9);
    for (int ci = 0; ci < CH; ++ci) {
        float xr[18];
        #pragma unroll
        for (int j = 0; j < 18; ++j) xr[j] = ld[ci][wi][h0 + j];
        #pragma unroll
        for (int c = 0; c < 4; ++c) {
            const float* wp = wb + (size_t)c*(CH*9) + ci*9;
            #pragma unroll
            for (int t = 0; t < 9; ++t) {
                const float wv = wp[t];
                #pragma unroll
                for (int k = 0; k < 10; ++k) acc[c][k] = fmaf(wv, xr[k+t], acc[c][k]);
            }
        }
    }
    #pragma unroll
    for (int c = 0; c < 4; ++c) {
        const size_t o = (size_t)b*CHW + (size_t)(co0 + c)*HW + (size_t)h0*WW + (w0 + wi);
        #pragma unroll
        for (int k = 0; k < 10; ++k) {
            const float s = src[o + (size_t)k*WW];
            dst[o + (size_t)k*WW] = s + 2.f*fmaxf(acc[c][k], 0.f);
        }
    }
}

// ===========================================================================
extern "C" void kernel_launch(void* const* d_in, const int* in_sizes, int n_in,
                              void* d_out, int out_size, void* d_ws, size_t ws_size,
                              hipStream_t stream)
{
    const float* x  = (const float*)d_in[0];
    const float* wd = (const float*)d_in[1];
    const float* wu = (const float*)d_in[2];
    const float* wr = (const float*)d_in[3];
    const float* wl = (const float*)d_in[4];

    const size_t NEED = 125829120ULL + 2ULL*WFRAG_HALVES*2ULL;  // 137,625,600 B

    if (ws_size >= NEED) {
        _Float16* HA  = (_Float16*)d_ws;
        _Float16* MA  = HA + NHWC_HALVES;
        _Float16* WHp = (_Float16*)((char*)d_ws + 125829120ULL);
        _Float16* WMp = WHp + WFRAG_HALVES;
        _Float16* HB  = (_Float16*)d_out;
        _Float16* MB  = HB + NHWC_HALVES;
        float* f32tmp = (float*)d_ws;   // reuses the A-pair region (dead by then)

        prep_weights<<<dim3(180), 256, 0, stream>>>(wd, wu, wr, wl, WHp, WMp);
        prep_acts<<<dim3(3, HH, BB), 256, 0, stream>>>(x, HA, MA);

        const int hoffs[10] = {1,2,5,10,20, 39,38,35,30,20};     // wd: +off, wu: H-off
        for (int s = 0; s < 10; ++s) {
            const _Float16* sH = (s & 1) ? HB : HA;
            const _Float16* sM = (s & 1) ? MB : MA;
            _Float16* dH = (s & 1) ? HA : HB;
            _Float16* dM = (s & 1) ? MA : MB;
            hconv_mfma<<<dim3(HH, BB), 256, 0, stream>>>(sH, sM, dH, dM,
                                                         WHp, WMp, s, hoffs[s]);
        }
        const int woffs[10] = {3,6,12,24,48, 93,90,84,72,48};    // wr: +off, wl: W-off
        for (int k = 0; k < 10; ++k) {
            const int s = 10 + k;
            const _Float16* sH = (s & 1) ? HB : HA;
            const _Float16* sM = (s & 1) ? MB : MA;
            _Float16* dH = (s & 1) ? HA : HB;
            _Float16* dM = (s & 1) ? MA : MB;
            const int fin = (s == 19);
            vconv_mfma<<<dim3(WW/2, BB), 256, 0, stream>>>(sH, sM, dH, dM,
                                                           WHp, WMp, s, woffs[k],
                                                           fin, f32tmp);
        }
        nhwc_to_nchw<<<dim3(3, HH, BB), 256, 0, stream>>>(f32tmp, (float*)d_out);
    } else {
        // fp32 fallback (round-1 path)
        float* out = (float*)d_out;
        float* ws  = (float*)d_ws;
        const size_t WSTEP = (size_t)WSTEP_F;
        const int hoffs[5] = {1, 2, 5, 10, 20};
        const int woffs[5] = {3, 6, 12, 24, 48};
        dim3 hgrid(HH, BB), vgrid(WW/2, BB);
        const float* src = x;
        int step = 0;
        for (int i = 0; i < 5; ++i) {
            float* dst = (step & 1) ? out : ws;
            hconv_step<<<hgrid, 256, 0, stream>>>(src, wd + i*WSTEP, dst, hoffs[i]);
            src = dst; ++step;
        }
        for (int i = 0; i < 5; ++i) {
            float* dst = (step & 1) ? out : ws;
            hconv_step<<<hgrid, 256, 0, stream>>>(src, wu + i*WSTEP, dst, (HH - hoffs[i]) % HH);
            src = dst; ++step;
        }
        for (int i = 0; i < 5; ++i) {
            float* dst = (step & 1) ? out : ws;
            vconv_step<<<vgrid, 256, 0, stream>>>(src, wr + i*WSTEP, dst, woffs[i]);
            src = dst; ++step;
        }
        for (int i = 0; i < 5; ++i) {
            float* dst = (step & 1) ? out : ws;
            vconv_step<<<vgrid, 256, 0, stream>>>(src, wl + i*WSTEP, dst, (WW - woffs[i]) % WW);
            src = dst; ++step;
        }
    }
}

// Round 3
// 4079.669 us; speedup vs baseline: 1.2312x; 1.0994x over previous
//
#include <hip/hip_runtime.h>
#include <cstdint>
#include <cstddef>

#define CH 128
#define HH 40
#define WW 96
#define BB 64
#define HW (HH*WW)          // 3840
#define CHW ((size_t)CH*HW) // 491520

typedef _Float16 half8  __attribute__((ext_vector_type(8)));
typedef _Float16 half4v __attribute__((ext_vector_type(4)));
typedef float    float4v __attribute__((ext_vector_type(4)));

#define MFMA16(a,b,c) __builtin_amdgcn_mfma_f32_16x16x32_f16((a),(b),(c),0,0,0)

#define SPLIT_SCALE 2048.0f
#define INV_SPLIT   (1.0f/2048.0f)

#define NHWC_HALVES (BB*HH*WW*CH)   // 31,457,280 halves = 62,914,560 B
#define WSTEP_F     (CH*CH*9)       // 147,456 fp32 per step
#define WFRAG_HALVES (20*9*4*8*64*8) // 2,949,120 halves per (h|m) weight bank

// Direct global->LDS (wave-uniform LDS base + lane*16; per-lane global src).
__device__ __forceinline__ void gload16(const _Float16* g, _Float16* l) {
    __builtin_amdgcn_global_load_lds(
        (const __attribute__((address_space(1))) void*)g,
        (__attribute__((address_space(3))) void*)l,
        16, 0, 0);
}

// ===========================================================================
// MFMA path
// ===========================================================================

// Pre-shuffle weights into A-fragment lane order, split h/m (m scaled x2048).
// Layout: WH[((s*9+t)*4+kq)*8+mt][lane][j] ; co=mt*16+(lane&15),
// ci=kq*32+(lane>>4)*8+j.
__global__ __launch_bounds__(256) void prep_weights(
    const float* __restrict__ wd, const float* __restrict__ wu,
    const float* __restrict__ wr, const float* __restrict__ wl,
    _Float16* __restrict__ WH, _Float16* __restrict__ WM)
{
    const int bx = blockIdx.x;          // s*9 + t
    const int s = bx / 9, t = bx % 9;
    const float* src;
    if (s < 5)       src = wd + (size_t)s*WSTEP_F;
    else if (s < 10) src = wu + (size_t)(s-5)*WSTEP_F;
    else if (s < 15) src = wr + (size_t)(s-10)*WSTEP_F;
    else             src = wl + (size_t)(s-15)*WSTEP_F;

    for (int idx = threadIdx.x; idx < 2048; idx += 256) {
        const int lane = idx & 63;
        const int mt   = (idx >> 6) & 7;
        const int kq   = idx >> 9;
        const int co   = mt*16 + (lane & 15);
        const int cib  = kq*32 + (lane >> 4)*8;
        const int F    = ((((s*9 + t)*4 + kq)*8 + mt)*64 + lane)*8;
        #pragma unroll
        for (int j = 0; j < 8; ++j) {
            const float w = src[(size_t)(co*CH + (cib + j))*9 + t];
            const _Float16 h = (_Float16)w;
            WH[F + j] = h;
            WM[F + j] = (_Float16)((w - (float)h) * SPLIT_SCALE);
        }
    }
}

// fp32 NCHW -> (h,m) fp16 pair in NHWC (ci contiguous).
__global__ __launch_bounds__(256) void prep_acts(
    const float* __restrict__ x, _Float16* __restrict__ H, _Float16* __restrict__ M)
{
    __shared__ float tile[CH][33];
    const int wt = blockIdx.x, h = blockIdx.y, b = blockIdx.z;
    const int tid = threadIdx.x;
    {
        const int wl = tid & 31, c0 = tid >> 5;
        for (int it = 0; it < 16; ++it) {
            const int ci = it*8 + c0;
            tile[ci][wl] = x[((size_t)(b*CH + ci)*HH + h)*WW + wt*32 + wl];
        }
    }
    __syncthreads();
    {
        const int ci = tid & 127, w0 = tid >> 7;
        for (int it = 0; it < 16; ++it) {
            const int wl = it*2 + w0;
            const float v = tile[ci][wl];
            const _Float16 hh = (_Float16)v;
            const int o = ((b*HH + h)*WW + wt*32 + wl)*CH + ci;
            H[o] = hh;
            M[o] = (_Float16)((v - (float)hh) * SPLIT_SCALE);
        }
    }
}

// Horizontal conv (1x9 along W, pad 4), rows rolled by hoff. One block per
// (b,h): M=128 co x N=96 w, K=128 ci, 9 taps via LDS row offset.
// LDS: pitch 128 halves (256B rows) + XOR swizzle ((row&7)<<3 on half index).
// Staging via global_load_lds (linear LDS dest, inverse-swizzled per-lane
// GLOBAL source — involution).
__global__ __launch_bounds__(256, 2) void hconv_mfma(
    const _Float16* __restrict__ srcH, const _Float16* __restrict__ srcM,
    _Float16* __restrict__ dstH, _Float16* __restrict__ dstM,
    const _Float16* __restrict__ WH, const _Float16* __restrict__ WM,
    int s, int hoff)
{
    __shared__ _Float16 sB[2][104*128];   // [h|m][row 0..103][ci 0..127]
    const int h = blockIdx.x, b = blockIdx.y;
    const int tid = threadIdx.x;
    const int hp = (h + hoff) % HH;
    const int lane = tid & 63, wave = tid >> 6;

    {   // stage rows 4..99 (input w = row-4) : 24 chunks of 4 rows, 6/wave
        const int rr = lane >> 4, slot = lane & 15;
        #pragma unroll
        for (int k = 0; k < 6; ++k) {
            const int c = wave*6 + k;
            const int rbase = 4 + 4*c;            // LDS row base (mult of 4)
            const int row = rbase + rr;
            const size_t goff = ((size_t)(b*HH + hp)*WW + (rbase - 4))*CH;
            const int so = rr*CH + ((slot ^ (row & 7))*8);
            gload16(srcH + goff + so, (_Float16*)&sB[0][rbase*128]);
            gload16(srcM + goff + so, (_Float16*)&sB[1][rbase*128]);
        }
        // zero halos: rows 0..3 and 100..103, both arrays (4 rows = 512 halves)
        const int zrow = (wave & 1)*100;
        const int arr  = wave >> 1;
        *(half8*)&sB[arr][zrow*128 + lane*8] = (half8){};
    }
    __syncthreads();

    const int n = lane & 15, quad = lane >> 4;
    const int mgrp = wave & 1, ngrp = wave >> 1;
    const int qs = quad*8;
#define BADDR(row, kq) ((row)*128 + ((((kq)*32) + qs) ^ ((((row) & 7)) << 3)))

    float4v acc0[4][3], acc1[4][3];
    #pragma unroll
    for (int i = 0; i < 4; ++i)
        #pragma unroll
        for (int j = 0; j < 3; ++j) {
            acc0[i][j] = (float4v){0.f,0.f,0.f,0.f};
            acc1[i][j] = (float4v){0.f,0.f,0.f,0.f};
        }

    int rowb[3];
    #pragma unroll
    for (int j = 0; j < 3; ++j) rowb[j] = (ngrp*3 + j)*16 + n;

    // F(it) = s*147456 + it*4096 + mgrp*2048 + lane*8 ; +i*512 per mt
    const size_t Fb = (size_t)s*147456 + (size_t)(mgrp*2048 + lane*8);

    half8 Wh[2][4], Wm[2][4];
    #pragma unroll
    for (int i = 0; i < 4; ++i) {            // preload it=0 -> bank 0
        Wh[0][i] = *(const half8*)(WH + Fb + i*512);
        Wm[0][i] = *(const half8*)(WM + Fb + i*512);
    }
    half8 pbh = *(const half8*)&sB[0][BADDR(rowb[0], 0)];   // (t=0,kq=0,j=0)
    half8 pbm = *(const half8*)&sB[1][BADDR(rowb[0], 0)];

    for (int t = 0; t < 9; ++t) {
        #pragma unroll
        for (int kq = 0; kq < 4; ++kq) {
            const int it  = t*4 + kq;
            const int itn = (it < 35) ? it + 1 : 35;   // clamp: last prefetch harmless
            const int pc  = kq & 1;                    // static after unroll
            const int pn  = pc ^ 1;
            {   // prefetch weights for it+1 into the other bank
                const _Float16* nH = WH + Fb + (size_t)itn*4096;
                const _Float16* nM = WM + Fb + (size_t)itn*4096;
                #pragma unroll
                for (int i = 0; i < 4; ++i) {
                    Wh[pn][i] = *(const half8*)(nH + i*512);
                    Wm[pn][i] = *(const half8*)(nM + i*512);
                }
            }
            const int tn = itn >> 2, kqn = itn & 3;
            #pragma unroll
            for (int j = 0; j < 3; ++j) {
                const half8 bh = pbh, bm = pbm;
                int nro;
                if (j < 2) nro = BADDR(rowb[j+1] + t, kq);
                else       nro = BADDR(rowb[0] + tn, kqn);
                pbh = *(const half8*)&sB[0][nro];
                pbm = *(const half8*)&sB[1][nro];
                __builtin_amdgcn_s_setprio(1);
                #pragma unroll
                for (int i = 0; i < 4; ++i) {
                    acc0[i][j] = MFMA16(Wh[pc][i], bh, acc0[i][j]);
                    acc1[i][j] = MFMA16(Wh[pc][i], bm, acc1[i][j]);
                    acc1[i][j] = MFMA16(Wm[pc][i], bh, acc1[i][j]);
                }
                __builtin_amdgcn_s_setprio(0);
            }
        }
    }
#undef BADDR

    const int spbase = (b*HH + h)*WW;
    #pragma unroll
    for (int i = 0; i < 4; ++i) {
        const int co = (mgrp*4 + i)*16 + quad*4;
        #pragma unroll
        for (int j = 0; j < 3; ++j) {
            const int w  = (ngrp*3 + j)*16 + n;
            const int sp = (spbase + w)*CH + co;
            const half4v oh = *(const half4v*)(srcH + sp);
            const half4v om = *(const half4v*)(srcM + sp);
            half4v zh, zm;
            #pragma unroll
            for (int r = 0; r < 4; ++r) {
                const float v = acc0[i][j][r] + acc1[i][j][r]*INV_SPLIT;
                const float y = (float)oh[r] + (float)om[r]*INV_SPLIT;
                const float z = y + 2.0f*fmaxf(v, 0.0f);
                const _Float16 a = (_Float16)z;
                zh[r] = a;
                zm[r] = (_Float16)((z - (float)a)*SPLIT_SCALE);
            }
            *(half4v*)(dstH + sp) = zh;
            *(half4v*)(dstM + sp) = zm;
        }
    }
}

// Vertical conv (9x1 along H, pad 4), cols rolled by woff. One block per
// (b, w-pair). N = 2 cols x 40 valid h = 80 outputs = 5 tiles of 16.
// BALANCED wave split: every wave iterates all 5 N-tiles and owns a 32-wide
// co slice (2 A-frags, mt = wave*2+i). 1080 MFMAs/wave, zero tail idle.
__global__ __launch_bounds__(256, 2) void vconv_mfma(
    const _Float16* __restrict__ srcH, const _Float16* __restrict__ srcM,
    _Float16* __restrict__ dstH, _Float16* __restrict__ dstM,
    const _Float16* __restrict__ WH, const _Float16* __restrict__ WM,
    int s, int woff, int final, float* __restrict__ f32out)
{
    __shared__ _Float16 sB[2][96*128];  // [h|m][col*48 + (h_in+4)][ci]
    const int wp = blockIdx.x, b = blockIdx.y;
    const int tid = threadIdx.x;
    const int lane = tid & 63, wave = tid >> 6;

    {   // stage 2 cols x 40 valid rows: 20 chunks of 4 rows, 5/wave
        const int rr = lane >> 4, slot = lane & 15;
        for (int k = wave; k < 20; k += 4) {
            const int col = (k >= 10);
            const int c = k - col*10;
            const int rbase = col*48 + 4 + 4*c;   // LDS row base (mult of 4)
            const int h0 = 4*c;                   // global h base
            const int wsrc = (wp*2 + col + woff) % WW;
            const size_t goff = ((size_t)(b*HH + h0)*WW + wsrc)*CH;
            const int row = rbase + rr;
            const int so = rr*(WW*CH) + ((slot ^ (row & 7))*8);
            gload16(srcH + goff + so, (_Float16*)&sB[0][rbase*128]);
            gload16(srcM + goff + so, (_Float16*)&sB[1][rbase*128]);
        }
        // zero halos: row bases {0,44,48,92}, 4 rows each, both arrays
        const int zrow = (wave & 1)*44 + (wave >> 1)*48;
        *(half8*)&sB[0][zrow*128 + lane*8] = (half8){};
        *(half8*)&sB[1][zrow*128 + lane*8] = (half8){};
    }
    __syncthreads();

    const int n = lane & 15, quad = lane >> 4;
    const int qs = quad*8;
#define BADDR(row, kq) ((row)*128 + ((((kq)*32) + qs) ^ ((((row) & 7)) << 3)))

    float4v acc0[2][5], acc1[2][5];
    #pragma unroll
    for (int i = 0; i < 2; ++i)
        #pragma unroll
        for (int j = 0; j < 5; ++j) {
            acc0[i][j] = (float4v){0.f,0.f,0.f,0.f};
            acc1[i][j] = (float4v){0.f,0.f,0.f,0.f};
        }

    int rowbse[5];
    #pragma unroll
    for (int j = 0; j < 5; ++j) {
        const int o = j*16 + n;               // 0..79, all valid
        const int col = (o >= 40);
        rowbse[j] = o + 8*col;                // halo'd LDS row base (t adds 0..8)
    }

    // F(it) = s*147456 + it*4096 + (wave*2+i)*512 + lane*8
    const size_t Fb = (size_t)s*147456 + (size_t)(wave*1024 + lane*8);

    half8 Wh[2][2], Wm[2][2];
    #pragma unroll
    for (int i = 0; i < 2; ++i) {            // preload it=0 -> bank 0
        Wh[0][i] = *(const half8*)(WH + Fb + i*512);
        Wm[0][i] = *(const half8*)(WM + Fb + i*512);
    }
    half8 pbh = *(const half8*)&sB[0][BADDR(rowbse[0], 0)];
    half8 pbm = *(const half8*)&sB[1][BADDR(rowbse[0], 0)];

    for (int t = 0; t < 9; ++t) {
        #pragma unroll
        for (int kq = 0; kq < 4; ++kq) {
            const int it  = t*4 + kq;
            const int itn = (it < 35) ? it + 1 : 35;
            const int pc  = kq & 1;           // static after unroll
            const int pn  = pc ^ 1;
            {   // prefetch weights for it+1 into the other bank (4 b128)
                const _Float16* nH = WH + Fb + (size_t)itn*4096;
                const _Float16* nM = WM + Fb + (size_t)itn*4096;
                #pragma unroll
                for (int i = 0; i < 2; ++i) {
                    Wh[pn][i] = *(const half8*)(nH + i*512);
                    Wm[pn][i] = *(const half8*)(nM + i*512);
                }
            }
            const int tn = itn >> 2, kqn = itn & 3;
            #pragma unroll
            for (int j = 0; j < 5; ++j) {
                const half8 bh = pbh, bm = pbm;
                const int nro = (j < 4) ? BADDR(rowbse[j+1] + t, kq)
                                        : BADDR(rowbse[0] + tn, kqn);
                pbh = *(const half8*)&sB[0][nro];
                pbm = *(const half8*)&sB[1][nro];
                __builtin_amdgcn_s_setprio(1);
                #pragma unroll
                for (int i = 0; i < 2; ++i) {
                    acc0[i][j] = MFMA16(Wh[pc][i], bh, acc0[i][j]);
                    acc1[i][j] = MFMA16(Wh[pc][i], bm, acc1[i][j]);
                }
                #pragma unroll
                for (int i = 0; i < 2; ++i)
                    acc1[i][j] = MFMA16(Wm[pc][i], bh, acc1[i][j]);
                __builtin_amdgcn_s_setprio(0);
            }
        }
    }
#undef BADDR

    #pragma unroll
    for (int i = 0; i < 2; ++i) {
        const int co = (wave*2 + i)*16 + quad*4;
        #pragma unroll
        for (int j = 0; j < 5; ++j) {
            const int o = j*16 + n;
            const int col = (o >= 40);
            const int h_out = o - 40*col;
            const int w_out = wp*2 + col;
            const int sp = ((b*HH + h_out)*WW + w_out)*CH + co;
            const half4v oh = *(const half4v*)(srcH + sp);
            const half4v om = *(const half4v*)(srcM + sp);
            if (final) {
                float4v z4;
                #pragma unroll
                for (int r = 0; r < 4; ++r) {
                    const float v = acc0[i][j][r] + acc1[i][j][r]*INV_SPLIT;
                    const float y = (float)oh[r] + (float)om[r]*INV_SPLIT;
                    z4[r] = y + 2.0f*fmaxf(v, 0.0f);
                }
                *(float4v*)(f32out + sp) = z4;
            } else {
                half4v zh, zm;
                #pragma unroll
                for (int r = 0; r < 4; ++r) {
                    const float v = acc0[i][j][r] + acc1[i][j][r]*INV_SPLIT;
                    const float y = (float)oh[r] + (float)om[r]*INV_SPLIT;
                    const float z = y + 2.0f*fmaxf(v, 0.0f);
                    const _Float16 a = (_Float16)z;
                    zh[r] = a;
                    zm[r] = (_Float16)((z - (float)a)*SPLIT_SCALE);
                }
                *(half4v*)(dstH + sp) = zh;
                *(half4v*)(dstM + sp) = zm;
            }
        }
    }
}

// fp32 NHWC -> fp32 NCHW (final output)
__global__ __launch_bounds__(256) void nhwc_to_nchw(
    const float* __restrict__ src, float* __restrict__ dst)
{
    __shared__ float tile[32][133];
    const int wt = blockIdx.x, h = blockIdx.y, b = blockIdx.z;
    const int tid = threadIdx.x;
    {
        const int ci = tid & 127, w0 = tid >> 7;
        for (int it = 0; it < 16; ++it) {
            const int wl = it*2 + w0;
            tile[wl][ci] = src[((size_t)(b*HH + h)*WW + wt*32 + wl)*CH + ci];
        }
    }
    __syncthreads();
    {
        const int wl = tid & 31, c0 = tid >> 5;
        for (int it = 0; it < 16; ++it) {
            const int ci = it*8 + c0;
            dst[((size_t)(b*CH + ci)*HH + h)*WW + wt*32 + wl] = tile[wl][ci];
        }
    }
}

// ===========================================================================
// Fallback fp32 vector path (round-1, proven correct) — used if ws too small.
// ===========================================================================
__global__ __launch_bounds__(256) void hconv_step(
    const float* __restrict__ src, const float* __restrict__ wgt,
    float* __restrict__ dst, int hoff)
{
    __shared__ float ld[CH][104];
    const int h = blockIdx.x, b = blockIdx.y, tid = threadIdx.x;
    const int hp = (h + hoff) % HH;
    const float* srow = src + (size_t)b*CHW + (size_t)hp*WW;
    for (int idx = tid; idx < CH*24; idx += 256) {
        int ci = idx / 24, j = idx % 24;
        float4 v = *reinterpret_cast<const float4*>(srow + (size_t)ci*HW + j*4);
        *reinterpret_cast<float4*>(&ld[ci][4 + 4*j]) = v;
    }
    if (tid < CH) {
        *reinterpret_cast<float4*>(&ld[tid][0])   = make_float4(0.f,0.f,0.f,0.f);
        *reinterpret_cast<float4*>(&ld[tid][100]) = make_float4(0.f,0.f,0.f,0.f);
    }
    __syncthreads();
    const int tx = tid & 7, ty = tid >> 3;
    const int w0 = tx*12, co0 = ty*4;
    float acc[4][12];
    #pragma unroll
    for (int c = 0; c < 4; ++c)
        #pragma unroll
        for (int k = 0; k < 12; ++k) acc[c][k] = 0.f;
    const float* wb = wgt + (size_t)co0*(CH*9);
    for (int ci = 0; ci < CH; ++ci) {
        float xr[20];
        #pragma unroll
        for (int j = 0; j < 5; ++j) {
            float4 v = *reinterpret_cast<const float4*>(&ld[ci][w0 + 4*j]);
            xr[4*j+0]=v.x; xr[4*j+1]=v.y; xr[4*j+2]=v.z; xr[4*j+3]=v.w;
        }
        #pragma unroll
        for (int c = 0; c < 4; ++c) {
            const float* wp = wb + (size_t)c*(CH*9) + ci*9;
            #pragma unroll
            for (int t = 0; t < 9; ++t) {
                const float wv = wp[t];
                #pragma unroll
                for (int k = 0; k < 12; ++k) acc[c][k] = fmaf(wv, xr[k+t], acc[c][k]);
            }
        }
    }
    const size_t obase = (size_t)b*CHW + (size_t)h*WW + w0;
    #pragma unroll
    for (int c = 0; c < 4; ++c) {
        const size_t o = obase + (size_t)(co0 + c)*HW;
        #pragma unroll
        for (int j = 0; j < 3; ++j) {
            float4 s = *reinterpret_cast<const float4*>(src + o + 4*j);
            float4 r;
            r.x = s.x + 2.f*fmaxf(acc[c][4*j+0], 0.f);
            r.y = s.y + 2.f*fmaxf(acc[c][4*j+1], 0.f);
            r.z = s.z + 2.f*fmaxf(acc[c][4*j+2], 0.f);
            r.w = s.w + 2.f*fmaxf(acc[c][4*j+3], 0.f);
            *reinterpret_cast<float4*>(dst + o + 4*j) = r;
        }
    }
}

__global__ __launch_bounds__(256) void vconv_step(
    const float* __restrict__ src, const float* __restrict__ wgt,
    float* __restrict__ dst, int woff)
{
    __shared__ float ld[CH][2][48];
    const int w0 = blockIdx.x*2, b = blockIdx.y, tid = threadIdx.x;
    const int w1 = (w0 + woff) % WW, w2 = (w0 + 1 + woff) % WW;
    const float* sb = src + (size_t)b*CHW;
    for (int idx = tid; idx < CH*HH; idx += 256) {
        int ci = idx / HH, hh = idx % HH;
        const float* p = sb + (size_t)ci*HW + (size_t)hh*WW;
        ld[ci][0][4 + hh] = p[w1];
        ld[ci][1][4 + hh] = p[w2];
    }
    if (tid < CH) {
        #pragma unroll
        for (int j = 0; j < 4; ++j) {
            ld[tid][0][j]=0.f; ld[tid][0][44+j]=0.f;
            ld[tid][1][j]=0.f; ld[tid][1][44+j]=0.f;
        }
    }
    __syncthreads();
    const int tx = tid & 7, ty = tid >> 3;
    const int wi = tx >> 2, h0 = (tx & 3)*10, co0 = ty*4;
    float acc[4][10];
    #pragma unroll
    for (int c = 0; c < 4; ++c)
        #pragma unroll
        for (int k = 0; k < 10; ++k) acc[c][k] = 0.f;
    const float* wb = wgt + (size_t)co0*(CH*9);
    for (int ci = 0; ci < CH; ++ci) {
        float xr[18];
        #pragma unroll
        for (int j = 0; j < 18; ++j) xr[j] = ld[ci][wi][h0 + j];
        #pragma unroll
        for (int c = 0; c < 4; ++c) {
            const float* wp = wb + (size_t)c*(CH*9) + ci*9;
            #pragma unroll
            for (int t = 0; t < 9; ++t) {
                const float wv = wp[t];
                #pragma unroll
                for (int k = 0; k < 10; ++k) acc[c][k] = fmaf(wv, xr[k+t], acc[c][k]);
            }
        }
    }
    #pragma unroll
    for (int c = 0; c < 4; ++c) {
        const size_t o = (size_t)b*CHW + (size_t)(co0 + c)*HW + (size_t)h0*WW + (w0 + wi);
        #pragma unroll
        for (int k = 0; k < 10; ++k) {
            const float s = src[o + (size_t)k*WW];
            dst[o + (size_t)k*WW] = s + 2.f*fmaxf(acc[c][k], 0.f);
        }
    }
}

// ===========================================================================
extern "C" void kernel_launch(void* const* d_in, const int* in_sizes, int n_in,
                              void* d_out, int out_size, void* d_ws, size_t ws_size,
                              hipStream_t stream)
{
    const float* x  = (const float*)d_in[0];
    const float* wd = (const float*)d_in[1];
    const float* wu = (const float*)d_in[2];
    const float* wr = (const float*)d_in[3];
    const float* wl = (const float*)d_in[4];

    const size_t NEED = 125829120ULL + 2ULL*WFRAG_HALVES*2ULL;  // 137,625,600 B

    if (ws_size >= NEED) {
        _Float16* HA  = (_Float16*)d_ws;
        _Float16* MA  = HA + NHWC_HALVES;
        _Float16* WHp = (_Float16*)((char*)d_ws + 125829120ULL);
        _Float16* WMp = WHp + WFRAG_HALVES;
        _Float16* HB  = (_Float16*)d_out;
        _Float16* MB  = HB + NHWC_HALVES;
        float* f32tmp = (float*)d_ws;   // reuses the A-pair region (dead by then)

        prep_weights<<<dim3(180), 256, 0, stream>>>(wd, wu, wr, wl, WHp, WMp);
        prep_acts<<<dim3(3, HH, BB), 256, 0, stream>>>(x, HA, MA);

        const int hoffs[10] = {1,2,5,10,20, 39,38,35,30,20};     // wd: +off, wu: H-off
        for (int s = 0; s < 10; ++s) {
            const _Float16* sH = (s & 1) ? HB : HA;
            const _Float16* sM = (s & 1) ? MB : MA;
            _Float16* dH = (s & 1) ? HA : HB;
            _Float16* dM = (s & 1) ? MA : MB;
            hconv_mfma<<<dim3(HH, BB), 256, 0, stream>>>(sH, sM, dH, dM,
                                                         WHp, WMp, s, hoffs[s]);
        }
        const int woffs[10] = {3,6,12,24,48, 93,90,84,72,48};    // wr: +off, wl: W-off
        for (int k = 0; k < 10; ++k) {
            const int s = 10 + k;
            const _Float16* sH = (s & 1) ? HB : HA;
            const _Float16* sM = (s & 1) ? MB : MA;
            _Float16* dH = (s & 1) ? HA : HB;
            _Float16* dM = (s & 1) ? MA : MB;
            const int fin = (s == 19);
            vconv_mfma<<<dim3(WW/2, BB), 256, 0, stream>>>(sH, sM, dH, dM,
                                                           WHp, WMp, s, woffs[k],
                                                           fin, f32tmp);
        }
        nhwc_to_nchw<<<dim3(3, HH, BB), 256, 0, stream>>>(f32tmp, (float*)d_out);
    } else {
        // fp32 fallback (round-1 path)
        float* out = (float*)d_out;
        float* ws  = (float*)d_ws;
        const size_t WSTEP = (size_t)WSTEP_F;
        const int hoffs[5] = {1, 2, 5, 10, 20};
        const int woffs[5] = {3, 6, 12, 24, 48};
        dim3 hgrid(HH, BB), vgrid(WW/2, BB);
        const float* src = x;
        int step = 0;
        for (int i = 0; i < 5; ++i) {
            float* dst = (step & 1) ? out : ws;
            hconv_step<<<hgrid, 256, 0, stream>>>(src, wd + i*WSTEP, dst, hoffs[i]);
            src = dst; ++step;
        }
        for (int i = 0; i < 5; ++i) {
            float* dst = (step & 1) ? out : ws;
            hconv_step<<<hgrid, 256, 0, stream>>>(src, wu + i*WSTEP, dst, (HH - hoffs[i]) % HH);
            src = dst; ++step;
        }
        for (int i = 0; i < 5; ++i) {
            float* dst = (step & 1) ? out : ws;
            vconv_step<<<vgrid, 256, 0, stream>>>(src, wr + i*WSTEP, dst, woffs[i]);
            src = dst; ++step;
        }
        for (int i = 0; i < 5; ++i) {
            float* dst = (step & 1) ? out : ws;
            vconv_step<<<vgrid, 256, 0, stream>>>(src, wl + i*WSTEP, dst, (WW - woffs[i]) % WW);
            src = dst; ++step;
        }
    }
}

// Round 4
// 4005.924 us; speedup vs baseline: 1.2538x; 1.0184x over previous
//
#include <hip/hip_runtime.h>
#include <cstdint>
#include <cstddef>

#define CH 128
#define HH 40
#define WW 96
#define BB 64
#define HW (HH*WW)          // 3840
#define CHW ((size_t)CH*HW) // 491520

typedef _Float16 half8  __attribute__((ext_vector_type(8)));
typedef _Float16 half4v __attribute__((ext_vector_type(4)));
typedef float    float4v __attribute__((ext_vector_type(4)));

#define MFMA16(a,b,c) __builtin_amdgcn_mfma_f32_16x16x32_f16((a),(b),(c),0,0,0)

#define SPLIT_SCALE 2048.0f
#define INV_SPLIT   (1.0f/2048.0f)

#define NHWC_HALVES (BB*HH*WW*CH)   // 31,457,280 halves = 62,914,560 B
#define WSTEP_F     (CH*CH*9)       // 147,456 fp32 per step
#define WFRAG_HALVES (20*9*4*8*64*8) // 2,949,120 halves per (h|m) weight bank

// Direct global->LDS (wave-uniform LDS base + lane*16; per-lane global src).
__device__ __forceinline__ void gload16(const _Float16* g, _Float16* l) {
    __builtin_amdgcn_global_load_lds(
        (const __attribute__((address_space(1))) void*)g,
        (__attribute__((address_space(3))) void*)l,
        16, 0, 0);
}

// ===========================================================================
// MFMA path
// ===========================================================================

// Pre-shuffle weights into A-fragment lane order, split h/m (m scaled x2048).
// Layout: WH[((s*9+t)*4+kq)*8+mt][lane][j] ; co=mt*16+(lane&15),
// ci=kq*32+(lane>>4)*8+j.
__global__ __launch_bounds__(256) void prep_weights(
    const float* __restrict__ wd, const float* __restrict__ wu,
    const float* __restrict__ wr, const float* __restrict__ wl,
    _Float16* __restrict__ WH, _Float16* __restrict__ WM)
{
    const int bx = blockIdx.x;          // s*9 + t
    const int s = bx / 9, t = bx % 9;
    const float* src;
    if (s < 5)       src = wd + (size_t)s*WSTEP_F;
    else if (s < 10) src = wu + (size_t)(s-5)*WSTEP_F;
    else if (s < 15) src = wr + (size_t)(s-10)*WSTEP_F;
    else             src = wl + (size_t)(s-15)*WSTEP_F;

    for (int idx = threadIdx.x; idx < 2048; idx += 256) {
        const int lane = idx & 63;
        const int mt   = (idx >> 6) & 7;
        const int kq   = idx >> 9;
        const int co   = mt*16 + (lane & 15);
        const int cib  = kq*32 + (lane >> 4)*8;
        const int F    = ((((s*9 + t)*4 + kq)*8 + mt)*64 + lane)*8;
        #pragma unroll
        for (int j = 0; j < 8; ++j) {
            const float w = src[(size_t)(co*CH + (cib + j))*9 + t];
            const _Float16 h = (_Float16)w;
            WH[F + j] = h;
            WM[F + j] = (_Float16)((w - (float)h) * SPLIT_SCALE);
        }
    }
}

// fp32 NCHW -> (h,m) fp16 pair in NHWC (ci contiguous).
__global__ __launch_bounds__(256) void prep_acts(
    const float* __restrict__ x, _Float16* __restrict__ H, _Float16* __restrict__ M)
{
    __shared__ float tile[CH][33];
    const int wt = blockIdx.x, h = blockIdx.y, b = blockIdx.z;
    const int tid = threadIdx.x;
    {
        const int wl = tid & 31, c0 = tid >> 5;
        for (int it = 0; it < 16; ++it) {
            const int ci = it*8 + c0;
            tile[ci][wl] = x[((size_t)(b*CH + ci)*HH + h)*WW + wt*32 + wl];
        }
    }
    __syncthreads();
    {
        const int ci = tid & 127, w0 = tid >> 7;
        for (int it = 0; it < 16; ++it) {
            const int wl = it*2 + w0;
            const float v = tile[ci][wl];
            const _Float16 hh = (_Float16)v;
            const int o = ((b*HH + h)*WW + wt*32 + wl)*CH + ci;
            H[o] = hh;
            M[o] = (_Float16)((v - (float)hh) * SPLIT_SCALE);
        }
    }
}

// Horizontal conv (1x9 along W, pad 4), rows rolled by hoff. One block per
// (b,h): M=128 co x N=96 w, K=128 ci, 9 taps via LDS row offset.
// BALANCED wave split (vconv-proven shape): every wave iterates all 6
// N-tiles and owns a 32-wide co slice (2 A-frags, mt = wave*2+i).
// 4 weight loads/iter (halves L1/L2 weight stream), 12 ds_reads, 36 MFMAs.
__global__ __launch_bounds__(256, 2) void hconv_mfma(
    const _Float16* __restrict__ srcH, const _Float16* __restrict__ srcM,
    _Float16* __restrict__ dstH, _Float16* __restrict__ dstM,
    const _Float16* __restrict__ WH, const _Float16* __restrict__ WM,
    int s, int hoff)
{
    __shared__ _Float16 sB[2][104*128];   // [h|m][row 0..103][ci 0..127]
    const int h = blockIdx.x, b = blockIdx.y;
    const int tid = threadIdx.x;
    const int hp = (h + hoff) % HH;
    const int lane = tid & 63, wave = tid >> 6;

    {   // stage rows 4..99 (input w = row-4) : 24 chunks of 4 rows, 6/wave
        const int rr = lane >> 4, slot = lane & 15;
        #pragma unroll
        for (int k = 0; k < 6; ++k) {
            const int c = wave*6 + k;
            const int rbase = 4 + 4*c;            // LDS row base (mult of 4)
            const int row = rbase + rr;
            const size_t goff = ((size_t)(b*HH + hp)*WW + (rbase - 4))*CH;
            const int so = rr*CH + ((slot ^ (row & 7))*8);
            gload16(srcH + goff + so, (_Float16*)&sB[0][rbase*128]);
            gload16(srcM + goff + so, (_Float16*)&sB[1][rbase*128]);
        }
        // zero halos: rows 0..3 and 100..103, both arrays (4 rows = 512 halves)
        const int zrow = (wave & 1)*100;
        const int arr  = wave >> 1;
        *(half8*)&sB[arr][zrow*128 + lane*8] = (half8){};
    }
    __syncthreads();

    const int n = lane & 15, quad = lane >> 4;
    const int qs = quad*8;
#define BADDR(row, kq) ((row)*128 + ((((kq)*32) + qs) ^ ((((row) & 7)) << 3)))

    float4v acc0[2][6], acc1[2][6];
    #pragma unroll
    for (int i = 0; i < 2; ++i)
        #pragma unroll
        for (int j = 0; j < 6; ++j) {
            acc0[i][j] = (float4v){0.f,0.f,0.f,0.f};
            acc1[i][j] = (float4v){0.f,0.f,0.f,0.f};
        }

    int rowb[6];
    #pragma unroll
    for (int j = 0; j < 6; ++j) rowb[j] = j*16 + n;

    // F(it) = s*147456 + it*4096 + (wave*2+i)*512 + lane*8
    const size_t Fb = (size_t)s*147456 + (size_t)(wave*1024 + lane*8);

    half8 Wh[2][2], Wm[2][2];
    #pragma unroll
    for (int i = 0; i < 2; ++i) {            // preload it=0 -> bank 0
        Wh[0][i] = *(const half8*)(WH + Fb + i*512);
        Wm[0][i] = *(const half8*)(WM + Fb + i*512);
    }
    half8 pbh = *(const half8*)&sB[0][BADDR(rowb[0], 0)];   // (t=0,kq=0,j=0)
    half8 pbm = *(const half8*)&sB[1][BADDR(rowb[0], 0)];

    for (int t = 0; t < 9; ++t) {
        #pragma unroll
        for (int kq = 0; kq < 4; ++kq) {
            const int it  = t*4 + kq;
            const int itn = (it < 35) ? it + 1 : 35;   // clamp: last prefetch harmless
            const int pc  = kq & 1;                    // static after unroll
            const int pn  = pc ^ 1;
            {   // prefetch weights for it+1 into the other bank (4 b128)
                const _Float16* nH = WH + Fb + (size_t)itn*4096;
                const _Float16* nM = WM + Fb + (size_t)itn*4096;
                #pragma unroll
                for (int i = 0; i < 2; ++i) {
                    Wh[pn][i] = *(const half8*)(nH + i*512);
                    Wm[pn][i] = *(const half8*)(nM + i*512);
                }
            }
            const int tn = itn >> 2, kqn = itn & 3;
            #pragma unroll
            for (int j = 0; j < 6; ++j) {
                const half8 bh = pbh, bm = pbm;
                const int nro = (j < 5) ? BADDR(rowb[j+1] + t, kq)
                                        : BADDR(rowb[0] + tn, kqn);
                pbh = *(const half8*)&sB[0][nro];
                pbm = *(const half8*)&sB[1][nro];
                __builtin_amdgcn_s_setprio(1);
                #pragma unroll
                for (int i = 0; i < 2; ++i) {
                    acc0[i][j] = MFMA16(Wh[pc][i], bh, acc0[i][j]);
                    acc1[i][j] = MFMA16(Wh[pc][i], bm, acc1[i][j]);
                }
                #pragma unroll
                for (int i = 0; i < 2; ++i)
                    acc1[i][j] = MFMA16(Wm[pc][i], bh, acc1[i][j]);
                __builtin_amdgcn_s_setprio(0);
            }
        }
    }
#undef BADDR

    const int spbase = (b*HH + h)*WW;
    #pragma unroll
    for (int i = 0; i < 2; ++i) {
        const int co = (wave*2 + i)*16 + quad*4;
        #pragma unroll
        for (int j = 0; j < 6; ++j) {
            const int w  = j*16 + n;
            const int sp = (spbase + w)*CH + co;
            const half4v oh = *(const half4v*)(srcH + sp);
            const half4v om = *(const half4v*)(srcM + sp);
            half4v zh, zm;
            #pragma unroll
            for (int r = 0; r < 4; ++r) {
                const float v = acc0[i][j][r] + acc1[i][j][r]*INV_SPLIT;
                const float y = (float)oh[r] + (float)om[r]*INV_SPLIT;
                const float z = y + 2.0f*fmaxf(v, 0.0f);
                const _Float16 a = (_Float16)z;
                zh[r] = a;
                zm[r] = (_Float16)((z - (float)a)*SPLIT_SCALE);
            }
            *(half4v*)(dstH + sp) = zh;
            *(half4v*)(dstM + sp) = zm;
        }
    }
}

// Vertical conv (9x1 along H, pad 4), cols rolled by woff. One block per
// (b, w-pair). N = 2 cols x 40 valid h = 80 outputs = 5 tiles of 16.
// BALANCED wave split: every wave iterates all 5 N-tiles and owns a 32-wide
// co slice (2 A-frags, mt = wave*2+i). 1080 MFMAs/wave, zero tail idle.
__global__ __launch_bounds__(256, 2) void vconv_mfma(
    const _Float16* __restrict__ srcH, const _Float16* __restrict__ srcM,
    _Float16* __restrict__ dstH, _Float16* __restrict__ dstM,
    const _Float16* __restrict__ WH, const _Float16* __restrict__ WM,
    int s, int woff, int final, float* __restrict__ f32out)
{
    __shared__ _Float16 sB[2][96*128];  // [h|m][col*48 + (h_in+4)][ci]
    const int wp = blockIdx.x, b = blockIdx.y;
    const int tid = threadIdx.x;
    const int lane = tid & 63, wave = tid >> 6;

    {   // stage 2 cols x 40 valid rows: 20 chunks of 4 rows, 5/wave
        const int rr = lane >> 4, slot = lane & 15;
        for (int k = wave; k < 20; k += 4) {
            const int col = (k >= 10);
            const int c = k - col*10;
            const int rbase = col*48 + 4 + 4*c;   // LDS row base (mult of 4)
            const int h0 = 4*c;                   // global h base
            const int wsrc = (wp*2 + col + woff) % WW;
            const size_t goff = ((size_t)(b*HH + h0)*WW + wsrc)*CH;
            const int row = rbase + rr;
            const int so = rr*(WW*CH) + ((slot ^ (row & 7))*8);
            gload16(srcH + goff + so, (_Float16*)&sB[0][rbase*128]);
            gload16(srcM + goff + so, (_Float16*)&sB[1][rbase*128]);
        }
        // zero halos: row bases {0,44,48,92}, 4 rows each, both arrays
        const int zrow = (wave & 1)*44 + (wave >> 1)*48;
        *(half8*)&sB[0][zrow*128 + lane*8] = (half8){};
        *(half8*)&sB[1][zrow*128 + lane*8] = (half8){};
    }
    __syncthreads();

    const int n = lane & 15, quad = lane >> 4;
    const int qs = quad*8;
#define BADDR(row, kq) ((row)*128 + ((((kq)*32) + qs) ^ ((((row) & 7)) << 3)))

    float4v acc0[2][5], acc1[2][5];
    #pragma unroll
    for (int i = 0; i < 2; ++i)
        #pragma unroll
        for (int j = 0; j < 5; ++j) {
            acc0[i][j] = (float4v){0.f,0.f,0.f,0.f};
            acc1[i][j] = (float4v){0.f,0.f,0.f,0.f};
        }

    int rowbse[5];
    #pragma unroll
    for (int j = 0; j < 5; ++j) {
        const int o = j*16 + n;               // 0..79, all valid
        const int col = (o >= 40);
        rowbse[j] = o + 8*col;                // halo'd LDS row base (t adds 0..8)
    }

    // F(it) = s*147456 + it*4096 + (wave*2+i)*512 + lane*8
    const size_t Fb = (size_t)s*147456 + (size_t)(wave*1024 + lane*8);

    half8 Wh[2][2], Wm[2][2];
    #pragma unroll
    for (int i = 0; i < 2; ++i) {            // preload it=0 -> bank 0
        Wh[0][i] = *(const half8*)(WH + Fb + i*512);
        Wm[0][i] = *(const half8*)(WM + Fb + i*512);
    }
    half8 pbh = *(const half8*)&sB[0][BADDR(rowbse[0], 0)];
    half8 pbm = *(const half8*)&sB[1][BADDR(rowbse[0], 0)];

    for (int t = 0; t < 9; ++t) {
        #pragma unroll
        for (int kq = 0; kq < 4; ++kq) {
            const int it  = t*4 + kq;
            const int itn = (it < 35) ? it + 1 : 35;
            const int pc  = kq & 1;           // static after unroll
            const int pn  = pc ^ 1;
            {   // prefetch weights for it+1 into the other bank (4 b128)
                const _Float16* nH = WH + Fb + (size_t)itn*4096;
                const _Float16* nM = WM + Fb + (size_t)itn*4096;
                #pragma unroll
                for (int i = 0; i < 2; ++i) {
                    Wh[pn][i] = *(const half8*)(nH + i*512);
                    Wm[pn][i] = *(const half8*)(nM + i*512);
                }
            }
            const int tn = itn >> 2, kqn = itn & 3;
            #pragma unroll
            for (int j = 0; j < 5; ++j) {
                const half8 bh = pbh, bm = pbm;
                const int nro = (j < 4) ? BADDR(rowbse[j+1] + t, kq)
                                        : BADDR(rowbse[0] + tn, kqn);
                pbh = *(const half8*)&sB[0][nro];
                pbm = *(const half8*)&sB[1][nro];
                __builtin_amdgcn_s_setprio(1);
                #pragma unroll
                for (int i = 0; i < 2; ++i) {
                    acc0[i][j] = MFMA16(Wh[pc][i], bh, acc0[i][j]);
                    acc1[i][j] = MFMA16(Wh[pc][i], bm, acc1[i][j]);
                }
                #pragma unroll
                for (int i = 0; i < 2; ++i)
                    acc1[i][j] = MFMA16(Wm[pc][i], bh, acc1[i][j]);
                __builtin_amdgcn_s_setprio(0);
            }
        }
    }
#undef BADDR

    #pragma unroll
    for (int i = 0; i < 2; ++i) {
        const int co = (wave*2 + i)*16 + quad*4;
        #pragma unroll
        for (int j = 0; j < 5; ++j) {
            const int o = j*16 + n;
            const int col = (o >= 40);
            const int h_out = o - 40*col;
            const int w_out = wp*2 + col;
            const int sp = ((b*HH + h_out)*WW + w_out)*CH + co;
            const half4v oh = *(const half4v*)(srcH + sp);
            const half4v om = *(const half4v*)(srcM + sp);
            if (final) {
                float4v z4;
                #pragma unroll
                for (int r = 0; r < 4; ++r) {
                    const float v = acc0[i][j][r] + acc1[i][j][r]*INV_SPLIT;
                    const float y = (float)oh[r] + (float)om[r]*INV_SPLIT;
                    z4[r] = y + 2.0f*fmaxf(v, 0.0f);
                }
                *(float4v*)(f32out + sp) = z4;
            } else {
                half4v zh, zm;
                #pragma unroll
                for (int r = 0; r < 4; ++r) {
                    const float v = acc0[i][j][r] + acc1[i][j][r]*INV_SPLIT;
                    const float y = (float)oh[r] + (float)om[r]*INV_SPLIT;
                    const float z = y + 2.0f*fmaxf(v, 0.0f);
                    const _Float16 a = (_Float16)z;
                    zh[r] = a;
                    zm[r] = (_Float16)((z - (float)a)*SPLIT_SCALE);
                }
                *(half4v*)(dstH + sp) = zh;
                *(half4v*)(dstM + sp) = zm;
            }
        }
    }
}

// fp32 NHWC -> fp32 NCHW (final output)
__global__ __launch_bounds__(256) void nhwc_to_nchw(
    const float* __restrict__ src, float* __restrict__ dst)
{
    __shared__ float tile[32][133];
    const int wt = blockIdx.x, h = blockIdx.y, b = blockIdx.z;
    const int tid = threadIdx.x;
    {
        const int ci = tid & 127, w0 = tid >> 7;
        for (int it = 0; it < 16; ++it) {
            const int wl = it*2 + w0;
            tile[wl][ci] = src[((size_t)(b*HH + h)*WW + wt*32 + wl)*CH + ci];
        }
    }
    __syncthreads();
    {
        const int wl = tid & 31, c0 = tid >> 5;
        for (int it = 0; it < 16; ++it) {
            const int ci = it*8 + c0;
            dst[((size_t)(b*CH + ci)*HH + h)*WW + wt*32 + wl] = tile[wl][ci];
        }
    }
}

// ===========================================================================
// Fallback fp32 vector path (round-1, proven correct) — used if ws too small.
// ===========================================================================
__global__ __launch_bounds__(256) void hconv_step(
    const float* __restrict__ src, const float* __restrict__ wgt,
    float* __restrict__ dst, int hoff)
{
    __shared__ float ld[CH][104];
    const int h = blockIdx.x, b = blockIdx.y, tid = threadIdx.x;
    const int hp = (h + hoff) % HH;
    const float* srow = src + (size_t)b*CHW + (size_t)hp*WW;
    for (int idx = tid; idx < CH*24; idx += 256) {
        int ci = idx / 24, j = idx % 24;
        float4 v = *reinterpret_cast<const float4*>(srow + (size_t)ci*HW + j*4);
        *reinterpret_cast<float4*>(&ld[ci][4 + 4*j]) = v;
    }
    if (tid < CH) {
        *reinterpret_cast<float4*>(&ld[tid][0])   = make_float4(0.f,0.f,0.f,0.f);
        *reinterpret_cast<float4*>(&ld[tid][100]) = make_float4(0.f,0.f,0.f,0.f);
    }
    __syncthreads();
    const int tx = tid & 7, ty = tid >> 3;
    const int w0 = tx*12, co0 = ty*4;
    float acc[4][12];
    #pragma unroll
    for (int c = 0; c < 4; ++c)
        #pragma unroll
        for (int k = 0; k < 12; ++k) acc[c][k] = 0.f;
    const float* wb = wgt + (size_t)co0*(CH*9);
    for (int ci = 0; ci < CH; ++ci) {
        float xr[20];
        #pragma unroll
        for (int j = 0; j < 5; ++j) {
            float4 v = *reinterpret_cast<const float4*>(&ld[ci][w0 + 4*j]);
            xr[4*j+0]=v.x; xr[4*j+1]=v.y; xr[4*j+2]=v.z; xr[4*j+3]=v.w;
        }
        #pragma unroll
        for (int c = 0; c < 4; ++c) {
            const float* wp = wb + (size_t)c*(CH*9) + ci*9;
            #pragma unroll
            for (int t = 0; t < 9; ++t) {
                const float wv = wp[t];
                #pragma unroll
                for (int k = 0; k < 12; ++k) acc[c][k] = fmaf(wv, xr[k+t], acc[c][k]);
            }
        }
    }
    const size_t obase = (size_t)b*CHW + (size_t)h*WW + w0;
    #pragma unroll
    for (int c = 0; c < 4; ++c) {
        const size_t o = obase + (size_t)(co0 + c)*HW;
        #pragma unroll
        for (int j = 0; j < 3; ++j) {
            float4 s = *reinterpret_cast<const float4*>(src + o + 4*j);
            float4 r;
            r.x = s.x + 2.f*fmaxf(acc[c][4*j+0], 0.f);
            r.y = s.y + 2.f*fmaxf(acc[c][4*j+1], 0.f);
            r.z = s.z + 2.f*fmaxf(acc[c][4*j+2], 0.f);
            r.w = s.w + 2.f*fmaxf(acc[c][4*j+3], 0.f);
            *reinterpret_cast<float4*>(dst + o + 4*j) = r;
        }
    }
}

__global__ __launch_bounds__(256) void vconv_step(
    const float* __restrict__ src, const float* __restrict__ wgt,
    float* __restrict__ dst, int woff)
{
    __shared__ float ld[CH][2][48];
    const int w0 = blockIdx.x*2, b = blockIdx.y, tid = threadIdx.x;
    const int w1 = (w0 + woff) % WW, w2 = (w0 + 1 + woff) % WW;
    const float* sb = src + (size_t)b*CHW;
    for (int idx = tid; idx < CH*HH; idx += 256) {
        int ci = idx / HH, hh = idx % HH;
        const float* p = sb + (size_t)ci*HW + (size_t)hh*WW;
        ld[ci][0][4 + hh] = p[w1];
        ld[ci][1][4 + hh] = p[w2];
    }
    if (tid < CH) {
        #pragma unroll
        for (int j = 0; j < 4; ++j) {
            ld[tid][0][j]=0.f; ld[tid][0][44+j]=0.f;
            ld[tid][1][j]=0.f; ld[tid][1][44+j]=0.f;
        }
    }
    __syncthreads();
    const int tx = tid & 7, ty = tid >> 3;
    const int wi = tx >> 2, h0 = (tx & 3)*10, co0 = ty*4;
    float acc[4][10];
    #pragma unroll
    for (int c = 0; c < 4; ++c)
        #pragma unroll
        for (int k = 0; k < 10; ++k) acc[c][k] = 0.f;
    const float* wb = wgt + (size_t)co0*(CH*9);
    for (int ci = 0; ci < CH; ++ci) {
        float xr[18];
        #pragma unroll
        for (int j = 0; j < 18; ++j) xr[j] = ld[ci][wi][h0 + j];
        #pragma unroll
        for (int c = 0; c < 4; ++c) {
            const float* wp = wb + (size_t)c*(CH*9) + ci*9;
            #pragma unroll
            for (int t = 0; t < 9; ++t) {
                const float wv = wp[t];
                #pragma unroll
                for (int k = 0; k < 10; ++k) acc[c][k] = fmaf(wv, xr[k+t], acc[c][k]);
            }
        }
    }
    #pragma unroll
    for (int c = 0; c < 4; ++c) {
        const size_t o = (size_t)b*CHW + (size_t)(co0 + c)*HW + (size_t)h0*WW + (w0 + wi);
        #pragma unroll
        for (int k = 0; k < 10; ++k) {
            const float s = src[o + (size_t)k*WW];
            dst[o + (size_t)k*WW] = s + 2.f*fmaxf(acc[c][k], 0.f);
        }
    }
}

// ===========================================================================
extern "C" void kernel_launch(void* const* d_in, const int* in_sizes, int n_in,
                              void* d_out, int out_size, void* d_ws, size_t ws_size,
                              hipStream_t stream)
{
    const float* x  = (const float*)d_in[0];
    const float* wd = (const float*)d_in[1];
    const float* wu = (const float*)d_in[2];
    const float* wr = (const float*)d_in[3];
    const float* wl = (const float*)d_in[4];

    const size_t NEED = 125829120ULL + 2ULL*WFRAG_HALVES*2ULL;  // 137,625,600 B

    if (ws_size >= NEED) {
        _Float16* HA  = (_Float16*)d_ws;
        _Float16* MA  = HA + NHWC_HALVES;
        _Float16* WHp = (_Float16*)((char*)d_ws + 125829120ULL);
        _Float16* WMp = WHp + WFRAG_HALVES;
        _Float16* HB  = (_Float16*)d_out;
        _Float16* MB  = HB + NHWC_HALVES;
        float* f32tmp = (float*)d_ws;   // reuses the A-pair region (dead by then)

        prep_weights<<<dim3(180), 256, 0, stream>>>(wd, wu, wr, wl, WHp, WMp);
        prep_acts<<<dim3(3, HH, BB), 256, 0, stream>>>(x, HA, MA);

        const int hoffs[10] = {1,2,5,10,20, 39,38,35,30,20};     // wd: +off, wu: H-off
        for (int s = 0; s < 10; ++s) {
            const _Float16* sH = (s & 1) ? HB : HA;
            const _Float16* sM = (s & 1) ? MB : MA;
            _Float16* dH = (s & 1) ? HA : HB;
            _Float16* dM = (s & 1) ? MA : MB;
            hconv_mfma<<<dim3(HH, BB), 256, 0, stream>>>(sH, sM, dH, dM,
                                                         WHp, WMp, s, hoffs[s]);
        }
        const int woffs[10] = {3,6,12,24,48, 93,90,84,72,48};    // wr: +off, wl: W-off
        for (int k = 0; k < 10; ++k) {
            const int s = 10 + k;
            const _Float16* sH = (s & 1) ? HB : HA;
            const _Float16* sM = (s & 1) ? MB : MA;
            _Float16* dH = (s & 1) ? HA : HB;
            _Float16* dM = (s & 1) ? MA : MB;
            const int fin = (s == 19);
            vconv_mfma<<<dim3(WW/2, BB), 256, 0, stream>>>(sH, sM, dH, dM,
                                                           WHp, WMp, s, woffs[k],
                                                           fin, f32tmp);
        }
        nhwc_to_nchw<<<dim3(3, HH, BB), 256, 0, stream>>>(f32tmp, (float*)d_out);
    } else {
        // fp32 fallback (round-1 path)
        float* out = (float*)d_out;
        float* ws  = (float*)d_ws;
        const size_t WSTEP = (size_t)WSTEP_F;
        const int hoffs[5] = {1, 2, 5, 10, 20};
        const int woffs[5] = {3, 6, 12, 24, 48};
        dim3 hgrid(HH, BB), vgrid(WW/2, BB);
        const float* src = x;
        int step = 0;
        for (int i = 0; i < 5; ++i) {
            float* dst = (step & 1) ? out : ws;
            hconv_step<<<hgrid, 256, 0, stream>>>(src, wd + i*WSTEP, dst, hoffs[i]);
            src = dst; ++step;
        }
        for (int i = 0; i < 5; ++i) {
            float* dst = (step & 1) ? out : ws;
            hconv_step<<<hgrid, 256, 0, stream>>>(src, wu + i*WSTEP, dst, (HH - hoffs[i]) % HH);
            src = dst; ++step;
        }
        for (int i = 0; i < 5; ++i) {
            float* dst = (step & 1) ? out : ws;
            vconv_step<<<vgrid, 256, 0, stream>>>(src, wr + i*WSTEP, dst, woffs[i]);
            src = dst; ++step;
        }
        for (int i = 0; i < 5; ++i) {
            float* dst = (step & 1) ? out : ws;
            vconv_step<<<vgrid, 256, 0, stream>>>(src, wl + i*WSTEP, dst, (WW - woffs[i]) % WW);
            src = dst; ++step;
        }
    }
}